// Round 7
// baseline (316.287 us; speedup 1.0000x reference)
//
#include <hip/hip_runtime.h>
#include <hip/hip_bf16.h>

typedef unsigned short u16;
typedef short s16x8 __attribute__((ext_vector_type(8)));
typedef float f32x4 __attribute__((ext_vector_type(4)));

#define EMB 768
#define NH 12
#define HD 64
#define BB 16
#define SS 1024
#define MTOK (BB*SS)      // 16384
#define NQKV (3*EMB)      // 2304
#define QSZ ((size_t)BB*NH*SS*HD)   // 12,582,912 elements

#define GLOBAL_AS const __attribute__((address_space(1))) void*
#define LDS_AS __attribute__((address_space(3))) void*

#if __has_builtin(__builtin_amdgcn_exp2f)
#define EXP2(x) __builtin_amdgcn_exp2f(x)
#else
#define EXP2(x) exp2f(x)
#endif

__device__ __forceinline__ u16 f2bf(float f){          // RNE
  unsigned u = __float_as_uint(f);
  u += 0x7FFFu + ((u >> 16) & 1u);
  return (u16)(u >> 16);
}
__device__ __forceinline__ u16 f2bf_trunc(float f){    // truncate (P only)
  return (u16)(__float_as_uint(f) >> 16);
}
__device__ __forceinline__ f32x4 mfma16(s16x8 a, s16x8 b, f32x4 c){
  return __builtin_amdgcn_mfma_f32_16x16x32_bf16(a, b, c, 0, 0, 0);
}

// ---------------- fused prep: x-convert + both weight transposes ------------
#define NBA 12288   // (QSZ/4)/256 exactly
#define NBB 1728    // (NQKV/32)*(EMB/32) = 72*24
#define NBC 576     // (EMB/32)*(EMB/32)  = 24*24

__device__ __forceinline__ void transpose_body(
    u16 (*tile)[33], const float* __restrict__ in, u16* __restrict__ out,
    int R, int C, int bxi, int byi){
  int bx = bxi * 32, by = byi * 32;
  int tx = threadIdx.x & 31, ty = threadIdx.x >> 5;
  #pragma unroll
  for(int i = 0; i < 32; i += 8)
    tile[ty + i][tx] = f2bf(in[(size_t)(by + ty + i) * C + bx + tx]);
  __syncthreads();
  #pragma unroll
  for(int i = 0; i < 32; i += 8)
    out[(size_t)(bx + ty + i) * R + by + tx] = tile[tx][ty + i];
}

__global__ __launch_bounds__(256) void prep_kernel(
    const float4* __restrict__ x4, ushort4* __restrict__ xb4,
    const float* __restrict__ qkv_w, u16* __restrict__ qkv_wT,
    const float* __restrict__ proj_w, u16* __restrict__ proj_wT){
  __shared__ u16 tile[32][33];
  int bid = blockIdx.x;
  if(bid < NBA){
    int i = bid * 256 + threadIdx.x;          // NBA*256 == QSZ/4 exactly
    float4 f = x4[i];
    ushort4 o;
    o.x = f2bf(f.x); o.y = f2bf(f.y); o.z = f2bf(f.z); o.w = f2bf(f.w);
    xb4[i] = o;
  } else if(bid < NBA + NBB){
    int bi = bid - NBA;                        // qkv_w [768,2304] -> [2304,768]
    transpose_body(tile, qkv_w, qkv_wT, EMB, NQKV, bi % (NQKV/32), bi / (NQKV/32));
  } else {
    int bi = bid - NBA - NBB;                  // proj_w [768,768] -> [768,768]
    transpose_body(tile, proj_w, proj_wT, EMB, EMB, bi % (EMB/32), bi / (EMB/32));
  }
}

// ---------------- 256x256 bf16 GEMM, K=768 — faithful m201 8-phase schedule --
// ROUND-7: round-6 was m196's known-bad variant (coarse stage cluster +
// counted vmcnt, no per-phase interleave) -> neutral. This is the verified
// template shape: per phase {stage 1 half-tile (2 gload_lds/thread) + ds_read
// one quadrant (12/4/8/0 x b128) -> s_barrier -> lgkmcnt(0)+sched_barrier ->
// setprio(1) 16 MFMA setprio(0) -> s_barrier}. vmcnt(2) ONLY at ph3/ph7
// (guarantees the whole next tile; one barrier before its first cross-wave
// read), never 0 mid-loop. Half-tiles: h0=A rows0-127, h1=A rows128-255,
// h2=B0-127, h3=B128-255; tile u staged in phases {prev-ph7,ph0,ph1,ph2}
// (odd u) / {ph3,ph4,ph5,ph6} (even u); buffer freed 2 barriers earlier.
// Swizzle byte-identical to the proven 0-conflict scheme.
template<int MODE>
__device__ __forceinline__ void gemm_body(
    const u16* __restrict__ A, const u16* __restrict__ Bt,
    const float* __restrict__ bias,
    void* __restrict__ out0, u16* __restrict__ out1, u16* __restrict__ out2){
  const int K = 768, NT = 12;
  __shared__ u16 As[2][256*64];          // 64 KB
  __shared__ u16 Bs[2][256*64];          // 64 KB
  int tid = threadIdx.x;

  // T1: bijective XCD-chunked swizzle (nwg % 8 == 0: 576 and 192)
  int gx = gridDim.x;
  int nwg = gx * gridDim.y;
  int L = blockIdx.y * gx + blockIdx.x;
  int nl = (L & 7) * (nwg >> 3) + (L >> 3);
  int m0 = (nl / gx) * 256, n0 = (nl % gx) * 256;

  int w = tid >> 6, lane = tid & 63, quad = lane >> 4, l15 = lane & 15;
  int wm = (w >> 2) * 128, wn = (w & 3) * 64;   // 2M x 4N waves, 128x64 each
  int rr = lane >> 3;          // row within an 8-row chunk-group
  int cp = lane & 7;           // 16B chunk position within row
  f32x4 acc[8][4] = {};

  // stage one half-tile: q=0,1 -> A rows q*128..+127; q=2,3 -> B (q-2)*128..
  auto stageQ = [&](int t, int q){
    int d = t & 1, k0 = t * 64;
    const u16* src = (q < 2) ? A : Bt;
    int base = (q < 2) ? m0 : n0;
    u16* dst = (q < 2) ? As[d] : Bs[d];
    int h = q & 1;
    #pragma unroll
    for(int it = 0; it < 2; ++it){
      int ci = h*16 + it*8 + w;          // 16 ci-groups per half
      int r  = ci * 8 + rr;
      int gc = (cp ^ (r & 7)) * 8;
      __builtin_amdgcn_global_load_lds(
          (GLOBAL_AS)(src + (size_t)(base + r) * K + k0 + gc),
          (LDS_AS)(dst + ci * 512 + lane * 8), 16, 0, 0);
    }
  };

  s16x8 a[8], b0[4], b1[4];
  auto dsA = [&](int d, int mh){         // 8 x ds_read_b128
    #pragma unroll
    for(int kk = 0; kk < 2; ++kk){
      int ch = ((kk*4 + quad) ^ (l15 & 7)) * 8;
      #pragma unroll
      for(int i = 0; i < 4; ++i)
        a[kk*4+i] = *(const s16x8*)&As[d][(wm + (mh*4+i)*16 + l15) * 64 + ch];
    }
  };
  auto dsB = [&](int d, int nh, s16x8* bb){   // 4 x ds_read_b128
    #pragma unroll
    for(int kk = 0; kk < 2; ++kk){
      int ch = ((kk*4 + quad) ^ (l15 & 7)) * 8;
      #pragma unroll
      for(int j = 0; j < 2; ++j)
        bb[kk*2+j] = *(const s16x8*)&Bs[d][(wn + (nh*2+j)*16 + l15) * 64 + ch];
    }
  };
  auto mfmaQ = [&](int mh, int nh, const s16x8* bb){  // 16 MFMA, one quadrant
    __builtin_amdgcn_s_setprio(1);
    #pragma unroll
    for(int kk = 0; kk < 2; ++kk)
      #pragma unroll
      for(int i = 0; i < 4; ++i)
        #pragma unroll
        for(int j = 0; j < 2; ++j)
          acc[mh*4+i][nh*2+j] = mfma16(a[kk*4+i], bb[kk*2+j], acc[mh*4+i][nh*2+j]);
    __builtin_amdgcn_s_setprio(0);
  };

#define PHASE_SYNC() do{ \
    __builtin_amdgcn_s_barrier(); \
    asm volatile("s_waitcnt lgkmcnt(0)" ::: "memory"); \
    __builtin_amdgcn_sched_barrier(0); \
  }while(0)
#define PHASE_END() do{ \
    __builtin_amdgcn_s_barrier(); \
    __builtin_amdgcn_sched_barrier(0); \
  }while(0)

  // prologue: tile0 fully + tile1.h0 in flight; guarantee tile0, keep h0
  stageQ(0,0); stageQ(0,1); stageQ(0,2); stageQ(0,3);
  stageQ(1,0);
  asm volatile("s_waitcnt vmcnt(2)" ::: "memory");
  __builtin_amdgcn_s_barrier();
  __builtin_amdgcn_sched_barrier(0);

  #pragma unroll
  for(int j = 0; j < NT/2; ++j){
    int t = 2*j;                               // even tile -> buf0, odd -> buf1
    // ph0: stage t+1.h1 ; read t:(A-mh0, B-nh0) ; mfma (0,0)
    stageQ(t+1, 1);
    dsA(0, 0); dsB(0, 0, b0);
    PHASE_SYNC(); mfmaQ(0, 0, b0); PHASE_END();
    // ph1: stage t+1.h2 ; read t:B-nh1 ; mfma (0,1)
    stageQ(t+1, 2);
    dsB(0, 1, b1);
    PHASE_SYNC(); mfmaQ(0, 1, b1); PHASE_END();
    // ph2: stage t+1.h3 ; read t:A-mh1 ; mfma (1,0)
    stageQ(t+1, 3);
    dsA(0, 1);
    PHASE_SYNC(); mfmaQ(1, 0, b0); PHASE_END();
    // ph3: stage t+2.h0 ; vmcnt(2) guarantees ALL of t+1 ; mfma (1,1)
    if(t+2 < NT){ stageQ(t+2, 0); asm volatile("s_waitcnt vmcnt(2)" ::: "memory"); }
    else        { asm volatile("s_waitcnt vmcnt(0)" ::: "memory"); }
    PHASE_SYNC(); mfmaQ(1, 1, b1); PHASE_END();
    // ph4: stage t+2.h1 ; read t+1:(A-mh0, B-nh0) ; mfma (0,0)
    if(t+2 < NT) stageQ(t+2, 1);
    dsA(1, 0); dsB(1, 0, b0);
    PHASE_SYNC(); mfmaQ(0, 0, b0); PHASE_END();
    // ph5: stage t+2.h2 ; read t+1:B-nh1 ; mfma (0,1)
    if(t+2 < NT) stageQ(t+2, 2);
    dsB(1, 1, b1);
    PHASE_SYNC(); mfmaQ(0, 1, b1); PHASE_END();
    // ph6: stage t+2.h3 ; read t+1:A-mh1 ; mfma (1,0)
    if(t+2 < NT) stageQ(t+2, 3);
    dsA(1, 1);
    PHASE_SYNC(); mfmaQ(1, 0, b0); PHASE_END();
    // ph7: stage t+3.h0 ; vmcnt(2) guarantees ALL of t+2 ; mfma (1,1)
    if(t+3 < NT){ stageQ(t+3, 0); asm volatile("s_waitcnt vmcnt(2)" ::: "memory"); }
    else if(t+2 < NT){ asm volatile("s_waitcnt vmcnt(0)" ::: "memory"); }
    PHASE_SYNC(); mfmaQ(1, 1, b1); PHASE_END();
  }
#undef PHASE_SYNC
#undef PHASE_END

  #pragma unroll
  for(int mt = 0; mt < 8; ++mt){
    #pragma unroll
    for(int nt = 0; nt < 4; ++nt){
      int n = n0 + wn + nt*16 + l15;
      float bv = bias[n];
      #pragma unroll
      for(int r = 0; r < 4; ++r){
        int m = m0 + wm + mt*16 + quad*4 + r;
        float v = acc[mt][nt][r] + bv;
        if(MODE == 1){
          ((float*)out0)[(size_t)m * EMB + n] = v;
        } else {
          u16 hv = f2bf(v);
          int which = n / EMB, rem = n - which * EMB;
          int h = rem >> 6, d = rem & 63;
          int bb = m >> 10, ss = m & 1023;
          size_t bh = (size_t)(bb * NH + h);
          if(which == 0)      ((u16*)out0)[(bh * SS + ss) * HD + d] = hv;
          else if(which == 1) out1[(bh * SS + ss) * HD + d] = hv;
          else                out2[(bh * HD + d) * SS + ss] = hv;   // V^T
        }
      }
    }
  }
}

__global__ __launch_bounds__(512, 2) void qkv_gemm_kernel(
    const u16* __restrict__ A, const u16* __restrict__ Bt,
    const float* __restrict__ bias,
    u16* __restrict__ Qo, u16* __restrict__ Ko, u16* __restrict__ Vo){
  gemm_body<0>(A, Bt, bias, Qo, Ko, Vo);
}
__global__ __launch_bounds__(512, 2) void proj_gemm_kernel(
    const u16* __restrict__ A, const u16* __restrict__ Bt,
    const float* __restrict__ bias, float* __restrict__ out){
  gemm_body<1>(A, Bt, bias, out, nullptr, nullptr);
}

// ---------------- attention: block = (bh, 128 q-rows), double-buffered -------
// Round-2 best-known form, UNCHANGED.
__global__ __launch_bounds__(256) void attn_kernel(
    const u16* __restrict__ Qws, const u16* __restrict__ Kws,
    const u16* __restrict__ Vtws, u16* __restrict__ attn){
  __shared__ u16 Ks[2][64*64];                    // [key][d]   16 KB
  __shared__ u16 Vs[2][64*64];                    // [d][key]   16 KB
  __shared__ __align__(16) u16 Ps[4][2][16][76];  // [wave][m][q][key] 19 KB
  int tid = threadIdx.x;
  int w = tid >> 6, lane = tid & 63, quad = lane >> 4, l15 = lane & 15;
  int bh = blockIdx.x;                 // x=bh: all q-blocks of a bh -> same XCD
  int b = bh / NH, h = bh - b * NH;
  int q0 = blockIdx.y * 128 + w * 32;
  const u16* Qbase = Qws  + (size_t)bh * SS * HD;
  const u16* Kbase = Kws  + (size_t)bh * SS * HD;
  const u16* Vbase = Vtws + (size_t)bh * HD * SS;

  s16x8 aq[2][2];
  #pragma unroll
  for(int m = 0; m < 2; m++){
    int qrow = q0 + m*16 + l15;
    #pragma unroll
    for(int kk = 0; kk < 2; kk++)
      aq[m][kk] = *(const s16x8*)(Qbase + (size_t)qrow * HD + kk*32 + quad*8);
  }

  f32x4 o[2][4] = {};
  float psum[2][4] = {};
  const float C1 = 0.125f * 1.44269504f;
  const float C0 = -30.0f * 1.44269504f;

  int krr = lane >> 3, kcp = lane & 7;   // staging decode: 8 rows x 8 chunks

  auto stageKV = [&](int p, int kt){
    #pragma unroll
    for(int it = 0; it < 2; ++it){
      int ins = it * 4 + w;              // 0..7
      int r   = ins * 8 + krr;           // 0..63
      int gck = (kcp ^ (r & 7)) * 8;
      __builtin_amdgcn_global_load_lds(
          (GLOBAL_AS)(Kbase + (size_t)(kt*64 + r) * HD + gck),
          (LDS_AS)(Ks[p] + ins * 512 + lane * 8), 16, 0, 0);
      __builtin_amdgcn_global_load_lds(
          (GLOBAL_AS)(Vbase + (size_t)r * SS + kt*64 + gck),
          (LDS_AS)(Vs[p] + ins * 512 + lane * 8), 16, 0, 0);
    }
  };

  stageKV(0, 0);
  int p = 0;
  for(int kt = 0; kt < 16; ++kt){        // 64 keys per iteration
    __syncthreads();                     // drains stage(p); publishes buf p
    if(kt < 15) stageKV(p ^ 1, kt + 1);  // prefetch overlaps compute

    // scores + exp + P  (4 key-tiles of 16)
    #pragma unroll
    for(int nt = 0; nt < 4; ++nt){
      s16x8 bk[2];
      #pragma unroll
      for(int kk = 0; kk < 2; kk++){
        int ch = ((kk*4 + quad) ^ (l15 & 7)) * 8;
        bk[kk] = *(const s16x8*)&Ks[p][(nt*16 + l15) * 64 + ch];
      }
      #pragma unroll
      for(int m = 0; m < 2; m++){
        f32x4 z = {};
        z = mfma16(aq[m][0], bk[0], z);
        z = mfma16(aq[m][1], bk[1], z);
        #pragma unroll
        for(int r = 0; r < 4; r++){
          float pv = EXP2(z[r] * C1 + C0);
          psum[m][r] += pv;
          Ps[w][m][quad*4 + r][nt*16 + l15] = f2bf_trunc(pv);
        }
      }
    }
    // PV: o(2x16x64) += P(2x16x64) @ V(64x64)
    #pragma unroll
    for(int k4 = 0; k4 < 2; k4++){
      s16x8 pa[2];
      #pragma unroll
      for(int m = 0; m < 2; m++)
        pa[m] = *(const s16x8*)&Ps[w][m][l15][k4*32 + quad*8];
      #pragma unroll
      for(int nt = 0; nt < 4; nt++){
        int ch = ((k4*4 + quad) ^ (l15 & 7)) * 8;
        s16x8 vb = *(const s16x8*)&Vs[p][(nt*16 + l15) * 64 + ch];
        #pragma unroll
        for(int m = 0; m < 2; m++)
          o[m][nt] = mfma16(pa[m], vb, o[m][nt]);
      }
    }
    p ^= 1;
  }

  // epilogue: out[b, s, h*64+d] = o / rowsum
  #pragma unroll
  for(int m = 0; m < 2; m++){
    #pragma unroll
    for(int r = 0; r < 4; r++){
      float s = psum[m][r];
      s += __shfl_xor(s, 1, 64);
      s += __shfl_xor(s, 2, 64);
      s += __shfl_xor(s, 4, 64);
      s += __shfl_xor(s, 8, 64);
      float inv = 1.0f / s;
      int srow = q0 + m*16 + quad*4 + r;
      size_t base = ((size_t)(b * SS + srow)) * EMB + h * HD;
      #pragma unroll
      for(int nt = 0; nt < 4; nt++)
        attn[base + nt*16 + l15] = f2bf(o[m][nt][r] * inv);
    }
  }
}

extern "C" void kernel_launch(void* const* d_in, const int* in_sizes, int n_in,
                              void* d_out, int out_size, void* d_ws, size_t ws_size,
                              hipStream_t stream){
  const float* x      = (const float*)d_in[0];
  const float* qkv_w  = (const float*)d_in[1];
  const float* qkv_b  = (const float*)d_in[2];
  const float* proj_w = (const float*)d_in[3];
  const float* proj_b = (const float*)d_in[4];

  char* ws = (char*)d_ws;
  u16* qkv_wT  = (u16*)ws; ws += (size_t)NQKV * EMB * 2;   // [2304,768] bf16
  u16* proj_wT = (u16*)ws; ws += (size_t)EMB * EMB * 2;    // [768,768] bf16
  u16* x_bf = (u16*)ws; ws += QSZ * 2;   // [16384,768] bf16; reused as attn out
  u16* Qws  = (u16*)ws; ws += QSZ * 2;                     // [bh,S,D]
  u16* Kws  = (u16*)ws; ws += QSZ * 2;                     // [bh,S,D]
  u16* Vtws = (u16*)ws; ws += QSZ * 2;                     // [bh,D,S]
  u16* attn = x_bf;

  prep_kernel<<<NBA + NBB + NBC, 256, 0, stream>>>(
      (const float4*)x, (ushort4*)x_bf, qkv_w, qkv_wT, proj_w, proj_wT);
  qkv_gemm_kernel<<<dim3(NQKV/256, MTOK/256), 512, 0, stream>>>(
      x_bf, qkv_wT, qkv_b, Qws, Kws, Vtws);
  attn_kernel<<<dim3(BB*NH, SS/128), 256, 0, stream>>>(Qws, Kws, Vtws, attn);
  proj_gemm_kernel<<<dim3(EMB/256, MTOK/256), 512, 0, stream>>>(
      attn, proj_wT, proj_b, (float*)d_out);
}

// Round 9
// 314.652 us; speedup vs baseline: 1.0052x; 1.0052x over previous
//
#include <hip/hip_runtime.h>
#include <hip/hip_bf16.h>

typedef unsigned short u16;
typedef unsigned int u32;
typedef short s16x8 __attribute__((ext_vector_type(8)));
typedef float f32x4 __attribute__((ext_vector_type(4)));

#define EMB 768
#define NH 12
#define HD 64
#define BB 16
#define SS 1024
#define MTOK (BB*SS)      // 16384
#define NQKV (3*EMB)      // 2304
#define QSZ ((size_t)BB*NH*SS*HD)   // 12,582,912 elements

#define GLOBAL_AS const __attribute__((address_space(1))) void*
#define LDS_AS __attribute__((address_space(3))) void*

#if __has_builtin(__builtin_amdgcn_exp2f)
#define EXP2(x) __builtin_amdgcn_exp2f(x)
#else
#define EXP2(x) exp2f(x)
#endif

__device__ __forceinline__ u16 f2bf(float f){          // RNE
  unsigned u = __float_as_uint(f);
  u += 0x7FFFu + ((u >> 16) & 1u);
  return (u16)(u >> 16);
}
__device__ __forceinline__ u16 f2bf_trunc(float f){    // truncate (P only)
  return (u16)(__float_as_uint(f) >> 16);
}
__device__ __forceinline__ f32x4 mfma16(s16x8 a, s16x8 b, f32x4 c){
  return __builtin_amdgcn_mfma_f32_16x16x32_bf16(a, b, c, 0, 0, 0);
}

// ---------------- fused prep: x-convert + both weight transposes ------------
#define NBA 12288   // (QSZ/4)/256 exactly
#define NBB 1728    // (NQKV/32)*(EMB/32) = 72*24
#define NBC 576     // (EMB/32)*(EMB/32)  = 24*24

__device__ __forceinline__ void transpose_body(
    u16 (*tile)[33], const float* __restrict__ in, u16* __restrict__ out,
    int R, int C, int bxi, int byi){
  int bx = bxi * 32, by = byi * 32;
  int tx = threadIdx.x & 31, ty = threadIdx.x >> 5;
  #pragma unroll
  for(int i = 0; i < 32; i += 8)
    tile[ty + i][tx] = f2bf(in[(size_t)(by + ty + i) * C + bx + tx]);
  __syncthreads();
  #pragma unroll
  for(int i = 0; i < 32; i += 8)
    out[(size_t)(bx + ty + i) * R + by + tx] = tile[tx][ty + i];
}

__global__ __launch_bounds__(256) void prep_kernel(
    const float4* __restrict__ x4, ushort4* __restrict__ xb4,
    const float* __restrict__ qkv_w, u16* __restrict__ qkv_wT,
    const float* __restrict__ proj_w, u16* __restrict__ proj_wT){
  __shared__ u16 tile[32][33];
  int bid = blockIdx.x;
  if(bid < NBA){
    int i = bid * 256 + threadIdx.x;          // NBA*256 == QSZ/4 exactly
    float4 f = x4[i];
    ushort4 o;
    o.x = f2bf(f.x); o.y = f2bf(f.y); o.z = f2bf(f.z); o.w = f2bf(f.w);
    xb4[i] = o;
  } else if(bid < NBA + NBB){
    int bi = bid - NBA;                        // qkv_w [768,2304] -> [2304,768]
    transpose_body(tile, qkv_w, qkv_wT, EMB, NQKV, bi % (NQKV/32), bi / (NQKV/32));
  } else {
    int bi = bid - NBA - NBB;                  // proj_w [768,768] -> [768,768]
    transpose_body(tile, proj_w, proj_wT, EMB, EMB, bi % (EMB/32), bi / (EMB/32));
  }
}

// ---------------- qkv GEMM: 128x128, double-buffered (BEST-KNOWN: 104 us) ----
// r1/r6/r7 restructures all landed 104-130 -> parked. This is round-5's body.
__global__ __launch_bounds__(256) void qkv_gemm_kernel(
    const u16* __restrict__ A, const u16* __restrict__ Bt,
    const float* __restrict__ bias,
    u16* __restrict__ Qo, u16* __restrict__ Ko, u16* __restrict__ Vo){
  const int K = 768;
  __shared__ u16 As[2][128*64];
  __shared__ u16 Bs[2][128*64];
  int tid = threadIdx.x;

  // T1: bijective XCD-chunked swizzle (nwg % 8 == 0: 2304)
  int gx = gridDim.x;
  int nwg = gx * gridDim.y;
  int L = blockIdx.y * gx + blockIdx.x;
  int nl = (L & 7) * (nwg >> 3) + (L >> 3);
  int m0 = (nl / gx) * 128, n0 = (nl % gx) * 128;

  int w = tid >> 6, lane = tid & 63, quad = lane >> 4, l15 = lane & 15;
  int wm = (w >> 1) * 64, wn = (w & 1) * 64;
  int rr = lane >> 3;          // row within a 1KB chunk-issue (0..7)
  int cp = lane & 7;           // 16B chunk position within row
  f32x4 acc[4][4] = {};

  auto stage = [&](int p, int k0){
    #pragma unroll
    for(int it = 0; it < 4; ++it){
      int ci = it * 4 + w;
      int r  = ci * 8 + rr;
      int gc = (cp ^ (r & 7)) * 8;
      __builtin_amdgcn_global_load_lds(
          (GLOBAL_AS)(A + (size_t)(m0 + r) * K + k0 + gc),
          (LDS_AS)(As[p] + ci * 512 + lane * 8), 16, 0, 0);
      __builtin_amdgcn_global_load_lds(
          (GLOBAL_AS)(Bt + (size_t)(n0 + r) * K + k0 + gc),
          (LDS_AS)(Bs[p] + ci * 512 + lane * 8), 16, 0, 0);
    }
  };

  stage(0, 0);
  int p = 0;
  for(int k0 = 0; k0 < K; k0 += 64){
    __syncthreads();
    if(k0 + 64 < K) stage(p ^ 1, k0 + 64);
    #pragma unroll
    for(int kk = 0; kk < 2; kk++){
      s16x8 a[4], b[4];
      int ch = ((kk * 4 + quad) ^ (l15 & 7)) * 8;
      #pragma unroll
      for(int i = 0; i < 4; i++){
        a[i] = *(const s16x8*)&As[p][(wm + i*16 + l15) * 64 + ch];
        b[i] = *(const s16x8*)&Bs[p][(wn + i*16 + l15) * 64 + ch];
      }
      #pragma unroll
      for(int mt = 0; mt < 4; mt++)
        #pragma unroll
        for(int nt = 0; nt < 4; nt++)
          acc[mt][nt] = mfma16(a[mt], b[nt], acc[mt][nt]);
    }
    p ^= 1;
  }

  #pragma unroll
  for(int mt = 0; mt < 4; mt++){
    #pragma unroll
    for(int nt = 0; nt < 4; nt++){
      int n = n0 + wn + nt*16 + l15;
      float bv = bias[n];
      #pragma unroll
      for(int r = 0; r < 4; r++){
        int m = m0 + wm + mt*16 + quad*4 + r;
        float v = acc[mt][nt][r] + bv;
        u16 hv = f2bf(v);
        int which = n / EMB, rem = n - which * EMB;
        int h = rem >> 6, d = rem & 63;
        int bb = m >> 10, ss = m & 1023;
        size_t bh = (size_t)(bb * NH + h);
        if(which == 0)      Qo[(bh * SS + ss) * HD + d] = hv;
        else if(which == 1) Ko[(bh * SS + ss) * HD + d] = hv;
        else                Vo[(bh * HD + d) * SS + ss] = hv;   // V^T
      }
    }
  }
}

// ---------------- proj GEMM: 256x256 8-phase (r7 form — proj improved ~7us) --
__global__ __launch_bounds__(512, 2) void proj_gemm_kernel(
    const u16* __restrict__ A, const u16* __restrict__ Bt,
    const float* __restrict__ bias, float* __restrict__ out){
  const int K = 768, NT = 12;
  __shared__ u16 As[2][256*64];
  __shared__ u16 Bs[2][256*64];
  int tid = threadIdx.x;

  int gx = gridDim.x;
  int nwg = gx * gridDim.y;
  int L = blockIdx.y * gx + blockIdx.x;
  int nl = (L & 7) * (nwg >> 3) + (L >> 3);
  int m0 = (nl / gx) * 256, n0 = (nl % gx) * 256;

  int w = tid >> 6, lane = tid & 63, quad = lane >> 4, l15 = lane & 15;
  int wm = (w >> 2) * 128, wn = (w & 3) * 64;
  int rr = lane >> 3;
  int cp = lane & 7;
  f32x4 acc[8][4] = {};

  auto stageQ = [&](int t, int q){
    int d = t & 1, k0 = t * 64;
    const u16* src = (q < 2) ? A : Bt;
    int base = (q < 2) ? m0 : n0;
    u16* dst = (q < 2) ? As[d] : Bs[d];
    int h = q & 1;
    #pragma unroll
    for(int it = 0; it < 2; ++it){
      int ci = h*16 + it*8 + w;
      int r  = ci * 8 + rr;
      int gc = (cp ^ (r & 7)) * 8;
      __builtin_amdgcn_global_load_lds(
          (GLOBAL_AS)(src + (size_t)(base + r) * K + k0 + gc),
          (LDS_AS)(dst + ci * 512 + lane * 8), 16, 0, 0);
    }
  };

  s16x8 a[8], b0[4], b1[4];
  auto dsA = [&](int d, int mh){
    #pragma unroll
    for(int kk = 0; kk < 2; ++kk){
      int ch = ((kk*4 + quad) ^ (l15 & 7)) * 8;
      #pragma unroll
      for(int i = 0; i < 4; ++i)
        a[kk*4+i] = *(const s16x8*)&As[d][(wm + (mh*4+i)*16 + l15) * 64 + ch];
    }
  };
  auto dsB = [&](int d, int nh, s16x8* bb){
    #pragma unroll
    for(int kk = 0; kk < 2; ++kk){
      int ch = ((kk*4 + quad) ^ (l15 & 7)) * 8;
      #pragma unroll
      for(int j = 0; j < 2; ++j)
        bb[kk*2+j] = *(const s16x8*)&Bs[d][(wn + (nh*2+j)*16 + l15) * 64 + ch];
    }
  };
  auto mfmaQ = [&](int mh, int nh, const s16x8* bb){
    __builtin_amdgcn_s_setprio(1);
    #pragma unroll
    for(int kk = 0; kk < 2; ++kk)
      #pragma unroll
      for(int i = 0; i < 4; ++i)
        #pragma unroll
        for(int j = 0; j < 2; ++j)
          acc[mh*4+i][nh*2+j] = mfma16(a[kk*4+i], bb[kk*2+j], acc[mh*4+i][nh*2+j]);
    __builtin_amdgcn_s_setprio(0);
  };

#define PHASE_SYNC() do{ \
    __builtin_amdgcn_s_barrier(); \
    asm volatile("s_waitcnt lgkmcnt(0)" ::: "memory"); \
    __builtin_amdgcn_sched_barrier(0); \
  }while(0)
#define PHASE_END() do{ \
    __builtin_amdgcn_s_barrier(); \
    __builtin_amdgcn_sched_barrier(0); \
  }while(0)

  stageQ(0,0); stageQ(0,1); stageQ(0,2); stageQ(0,3);
  stageQ(1,0);
  asm volatile("s_waitcnt vmcnt(2)" ::: "memory");
  __builtin_amdgcn_s_barrier();
  __builtin_amdgcn_sched_barrier(0);

  #pragma unroll
  for(int j = 0; j < NT/2; ++j){
    int t = 2*j;
    stageQ(t+1, 1);
    dsA(0, 0); dsB(0, 0, b0);
    PHASE_SYNC(); mfmaQ(0, 0, b0); PHASE_END();
    stageQ(t+1, 2);
    dsB(0, 1, b1);
    PHASE_SYNC(); mfmaQ(0, 1, b1); PHASE_END();
    stageQ(t+1, 3);
    dsA(0, 1);
    PHASE_SYNC(); mfmaQ(1, 0, b0); PHASE_END();
    if(t+2 < NT){ stageQ(t+2, 0); asm volatile("s_waitcnt vmcnt(2)" ::: "memory"); }
    else        { asm volatile("s_waitcnt vmcnt(0)" ::: "memory"); }
    PHASE_SYNC(); mfmaQ(1, 1, b1); PHASE_END();
    if(t+2 < NT) stageQ(t+2, 1);
    dsA(1, 0); dsB(1, 0, b0);
    PHASE_SYNC(); mfmaQ(0, 0, b0); PHASE_END();
    if(t+2 < NT) stageQ(t+2, 2);
    dsB(1, 1, b1);
    PHASE_SYNC(); mfmaQ(0, 1, b1); PHASE_END();
    if(t+2 < NT) stageQ(t+2, 3);
    dsA(1, 1);
    PHASE_SYNC(); mfmaQ(1, 0, b0); PHASE_END();
    if(t+3 < NT){ stageQ(t+3, 0); asm volatile("s_waitcnt vmcnt(2)" ::: "memory"); }
    else if(t+2 < NT){ asm volatile("s_waitcnt vmcnt(0)" ::: "memory"); }
    PHASE_SYNC(); mfmaQ(1, 1, b1); PHASE_END();
  }
#undef PHASE_SYNC
#undef PHASE_END

  #pragma unroll
  for(int mt = 0; mt < 8; ++mt){
    #pragma unroll
    for(int nt = 0; nt < 4; ++nt){
      int n = n0 + wn + nt*16 + l15;
      float bv = bias[n];
      #pragma unroll
      for(int r = 0; r < 4; ++r){
        int m = m0 + wm + mt*16 + quad*4 + r;
        out[(size_t)m * EMB + n] = acc[mt][nt][r] + bv;
      }
    }
  }
}

// ---------------- attention: block = (bh, 128 q-rows), double-buffered -------
// ROUND-8/9: swapped-operand QK^T. mfma(K_frag, Q_frag) puts 4 CONSECUTIVE
// k in each lane (row=quad*4+r -> k, col=l15 -> q), so the 32 scalar
// ds_write_b16 P-stores (the diagnosed ~150cyc/wave/kt serial cost) become
// 8 packed ds_write_b64. PV read layout unchanged: Ps[q=l15][k4*32+quad*8].
// Row-sums become lane-local partials: psum[m] scalar, reduced via
// shfl_xor(16,32) + per-row shfl redistribute in the epilogue.
__global__ __launch_bounds__(256) void attn_kernel(
    const u16* __restrict__ Qws, const u16* __restrict__ Kws,
    const u16* __restrict__ Vtws, u16* __restrict__ attn){
  __shared__ u16 Ks[2][64*64];                    // [key][d]   16 KB
  __shared__ u16 Vs[2][64*64];                    // [d][key]   16 KB
  __shared__ __align__(16) u16 Ps[4][2][16][76];  // [wave][m][q][key] 19 KB
  int tid = threadIdx.x;
  int w = tid >> 6, lane = tid & 63, quad = lane >> 4, l15 = lane & 15;
  int bh = blockIdx.x;                 // x=bh: all q-blocks of a bh -> same XCD
  int b = bh / NH, h = bh - b * NH;
  int q0 = blockIdx.y * 128 + w * 32;
  const u16* Qbase = Qws  + (size_t)bh * SS * HD;
  const u16* Kbase = Kws  + (size_t)bh * SS * HD;
  const u16* Vbase = Vtws + (size_t)bh * HD * SS;

  s16x8 aq[2][2];
  #pragma unroll
  for(int m = 0; m < 2; m++){
    int qrow = q0 + m*16 + l15;
    #pragma unroll
    for(int kk = 0; kk < 2; kk++)
      aq[m][kk] = *(const s16x8*)(Qbase + (size_t)qrow * HD + kk*32 + quad*8);
  }

  f32x4 o[2][4] = {};
  float psum[2] = {};
  const float C1 = 0.125f * 1.44269504f;
  const float C0 = -30.0f * 1.44269504f;

  int krr = lane >> 3, kcp = lane & 7;   // staging decode: 8 rows x 8 chunks

  auto stageKV = [&](int p, int kt){
    #pragma unroll
    for(int it = 0; it < 2; ++it){
      int ins = it * 4 + w;              // 0..7
      int r   = ins * 8 + krr;           // 0..63
      int gck = (kcp ^ (r & 7)) * 8;
      __builtin_amdgcn_global_load_lds(
          (GLOBAL_AS)(Kbase + (size_t)(kt*64 + r) * HD + gck),
          (LDS_AS)(Ks[p] + ins * 512 + lane * 8), 16, 0, 0);
      __builtin_amdgcn_global_load_lds(
          (GLOBAL_AS)(Vbase + (size_t)r * SS + kt*64 + gck),
          (LDS_AS)(Vs[p] + ins * 512 + lane * 8), 16, 0, 0);
    }
  };

  stageKV(0, 0);
  int p = 0;
  for(int kt = 0; kt < 16; ++kt){        // 64 keys per iteration
    __syncthreads();                     // drains stage(p); publishes buf p
    if(kt < 15) stageKV(p ^ 1, kt + 1);  // prefetch overlaps compute

    // scores + exp + P (4 key-tiles of 16) — SWAPPED operands:
    // z row = k (quad*4+r within nt-tile), z col = q (l15)
    #pragma unroll
    for(int nt = 0; nt < 4; ++nt){
      s16x8 bk[2];
      #pragma unroll
      for(int kk = 0; kk < 2; kk++){
        int ch = ((kk*4 + quad) ^ (l15 & 7)) * 8;
        bk[kk] = *(const s16x8*)&Ks[p][(nt*16 + l15) * 64 + ch];
      }
      #pragma unroll
      for(int m = 0; m < 2; m++){
        f32x4 z = {};
        z = mfma16(bk[0], aq[m][0], z);
        z = mfma16(bk[1], aq[m][1], z);
        float p0 = EXP2(z[0] * C1 + C0);
        float p1 = EXP2(z[1] * C1 + C0);
        float p2 = EXP2(z[2] * C1 + C0);
        float p3 = EXP2(z[3] * C1 + C0);
        psum[m] += (p0 + p1) + (p2 + p3);
        uint2 pk;
        pk.x = (u32)f2bf_trunc(p0) | ((u32)f2bf_trunc(p1) << 16);
        pk.y = (u32)f2bf_trunc(p2) | ((u32)f2bf_trunc(p3) << 16);
        *(uint2*)&Ps[w][m][l15][nt*16 + quad*4] = pk;   // 4 consecutive k
      }
    }
    // PV: o(2x16x64) += P(2x16x64) @ V(64x64)
    #pragma unroll
    for(int k4 = 0; k4 < 2; k4++){
      s16x8 pa[2];
      #pragma unroll
      for(int m = 0; m < 2; m++)
        pa[m] = *(const s16x8*)&Ps[w][m][l15][k4*32 + quad*8];
      #pragma unroll
      for(int nt = 0; nt < 4; nt++){
        int ch = ((k4*4 + quad) ^ (l15 & 7)) * 8;
        s16x8 vb = *(const s16x8*)&Vs[p][(nt*16 + l15) * 64 + ch];
        #pragma unroll
        for(int m = 0; m < 2; m++)
          o[m][nt] = mfma16(pa[m], vb, o[m][nt]);
      }
    }
    p ^= 1;
  }

  // epilogue: rowsum lives at lane l15==q after quad-reduction; redistribute
  // to the o-layout rows (quad*4+r) via shfl, then scale and store.
  #pragma unroll
  for(int m = 0; m < 2; m++){
    float s = psum[m];
    s += __shfl_xor(s, 16, 64);
    s += __shfl_xor(s, 32, 64);          // lane x holds rowsum for q = x&15
    #pragma unroll
    for(int r = 0; r < 4; r++){
      float inv = 1.0f / __shfl(s, quad*4 + r, 64);
      int srow = q0 + m*16 + quad*4 + r;
      size_t base = ((size_t)(b * SS + srow)) * EMB + h * HD;
      #pragma unroll
      for(int nt = 0; nt < 4; nt++)
        attn[base + nt*16 + l15] = f2bf(o[m][nt][r] * inv);
    }
  }
}

extern "C" void kernel_launch(void* const* d_in, const int* in_sizes, int n_in,
                              void* d_out, int out_size, void* d_ws, size_t ws_size,
                              hipStream_t stream){
  const float* x      = (const float*)d_in[0];
  const float* qkv_w  = (const float*)d_in[1];
  const float* qkv_b  = (const float*)d_in[2];
  const float* proj_w = (const float*)d_in[3];
  const float* proj_b = (const float*)d_in[4];

  char* ws = (char*)d_ws;
  u16* qkv_wT  = (u16*)ws; ws += (size_t)NQKV * EMB * 2;   // [2304,768] bf16
  u16* proj_wT = (u16*)ws; ws += (size_t)EMB * EMB * 2;    // [768,768] bf16
  u16* x_bf = (u16*)ws; ws += QSZ * 2;   // [16384,768] bf16; reused as attn out
  u16* Qws  = (u16*)ws; ws += QSZ * 2;                     // [bh,S,D]
  u16* Kws  = (u16*)ws; ws += QSZ * 2;                     // [bh,S,D]
  u16* Vtws = (u16*)ws; ws += QSZ * 2;                     // [bh,D,S]
  u16* attn = x_bf;

  prep_kernel<<<NBA + NBB + NBC, 256, 0, stream>>>(
      (const float4*)x, (ushort4*)x_bf, qkv_w, qkv_wT, proj_w, proj_wT);
  qkv_gemm_kernel<<<dim3(NQKV/128, MTOK/128), 256, 0, stream>>>(
      x_bf, qkv_wT, qkv_b, Qws, Kws, Vtws);
  attn_kernel<<<dim3(BB*NH, SS/128), 256, 0, stream>>>(Qws, Kws, Vtws, attn);
  proj_gemm_kernel<<<dim3(EMB/256, MTOK/256), 512, 0, stream>>>(
      attn, proj_wT, proj_b, (float*)d_out);
}

// Round 10
// 294.588 us; speedup vs baseline: 1.0737x; 1.0681x over previous
//
#include <hip/hip_runtime.h>
#include <hip/hip_bf16.h>

typedef unsigned short u16;
typedef unsigned int u32;
typedef short s16x8 __attribute__((ext_vector_type(8)));
typedef float f32x4 __attribute__((ext_vector_type(4)));

#define EMB 768
#define NH 12
#define HD 64
#define BB 16
#define SS 1024
#define MTOK (BB*SS)      // 16384
#define NQKV (3*EMB)      // 2304
#define QSZ ((size_t)BB*NH*SS*HD)   // 12,582,912 elements

#define GLOBAL_AS const __attribute__((address_space(1))) void*
#define LDS_AS __attribute__((address_space(3))) void*

#if __has_builtin(__builtin_amdgcn_exp2f)
#define EXP2(x) __builtin_amdgcn_exp2f(x)
#else
#define EXP2(x) exp2f(x)
#endif

__device__ __forceinline__ u16 f2bf(float f){          // RNE
  unsigned u = __float_as_uint(f);
  u += 0x7FFFu + ((u >> 16) & 1u);
  return (u16)(u >> 16);
}
__device__ __forceinline__ u16 f2bf_trunc(float f){    // truncate (P only)
  return (u16)(__float_as_uint(f) >> 16);
}
__device__ __forceinline__ f32x4 mfma16(s16x8 a, s16x8 b, f32x4 c){
  return __builtin_amdgcn_mfma_f32_16x16x32_bf16(a, b, c, 0, 0, 0);
}

// ---------------- fused prep: x-convert + both weight transposes ------------
#define NBA 12288   // (QSZ/4)/256 exactly
#define NBB 1728    // (NQKV/32)*(EMB/32) = 72*24
#define NBC 576     // (EMB/32)*(EMB/32)  = 24*24

__device__ __forceinline__ void transpose_body(
    u16 (*tile)[33], const float* __restrict__ in, u16* __restrict__ out,
    int R, int C, int bxi, int byi){
  int bx = bxi * 32, by = byi * 32;
  int tx = threadIdx.x & 31, ty = threadIdx.x >> 5;
  #pragma unroll
  for(int i = 0; i < 32; i += 8)
    tile[ty + i][tx] = f2bf(in[(size_t)(by + ty + i) * C + bx + tx]);
  __syncthreads();
  #pragma unroll
  for(int i = 0; i < 32; i += 8)
    out[(size_t)(bx + ty + i) * R + by + tx] = tile[tx][ty + i];
}

__global__ __launch_bounds__(256) void prep_kernel(
    const float4* __restrict__ x4, ushort4* __restrict__ xb4,
    const float* __restrict__ qkv_w, u16* __restrict__ qkv_wT,
    const float* __restrict__ proj_w, u16* __restrict__ proj_wT){
  __shared__ u16 tile[32][33];
  int bid = blockIdx.x;
  if(bid < NBA){
    int i = bid * 256 + threadIdx.x;          // NBA*256 == QSZ/4 exactly
    float4 f = x4[i];
    ushort4 o;
    o.x = f2bf(f.x); o.y = f2bf(f.y); o.z = f2bf(f.z); o.w = f2bf(f.w);
    xb4[i] = o;
  } else if(bid < NBA + NBB){
    int bi = bid - NBA;                        // qkv_w [768,2304] -> [2304,768]
    transpose_body(tile, qkv_w, qkv_wT, EMB, NQKV, bi % (NQKV/32), bi / (NQKV/32));
  } else {
    int bi = bid - NBA - NBB;                  // proj_w [768,768] -> [768,768]
    transpose_body(tile, proj_w, proj_wT, EMB, EMB, bi % (EMB/32), bi / (EMB/32));
  }
}

// ---------------- qkv GEMM: 128x128, double-buffered (BEST-KNOWN: 103.4 us) --
// ROUND-10: V^T epilogue packs 4 consecutive-s u16 into one dwordx2 store
// (global stores ARE issue/coalesce-bound, unlike the LDS P-store case where
// r9 proved packing null: LDS wave64 b64 >= 4cyc = same 32 LDS cycles as the
// bank-optimal scalar pattern). Q/K branches and everything else untouched.
__global__ __launch_bounds__(256) void qkv_gemm_kernel(
    const u16* __restrict__ A, const u16* __restrict__ Bt,
    const float* __restrict__ bias,
    u16* __restrict__ Qo, u16* __restrict__ Ko, u16* __restrict__ Vo){
  const int K = 768;
  __shared__ u16 As[2][128*64];
  __shared__ u16 Bs[2][128*64];
  int tid = threadIdx.x;

  // T1: bijective XCD-chunked swizzle (nwg % 8 == 0: 2304)
  int gx = gridDim.x;
  int nwg = gx * gridDim.y;
  int L = blockIdx.y * gx + blockIdx.x;
  int nl = (L & 7) * (nwg >> 3) + (L >> 3);
  int m0 = (nl / gx) * 128, n0 = (nl % gx) * 128;

  int w = tid >> 6, lane = tid & 63, quad = lane >> 4, l15 = lane & 15;
  int wm = (w >> 1) * 64, wn = (w & 1) * 64;
  int rr = lane >> 3;          // row within a 1KB chunk-issue (0..7)
  int cp = lane & 7;           // 16B chunk position within row
  f32x4 acc[4][4] = {};

  auto stage = [&](int p, int k0){
    #pragma unroll
    for(int it = 0; it < 4; ++it){
      int ci = it * 4 + w;
      int r  = ci * 8 + rr;
      int gc = (cp ^ (r & 7)) * 8;
      __builtin_amdgcn_global_load_lds(
          (GLOBAL_AS)(A + (size_t)(m0 + r) * K + k0 + gc),
          (LDS_AS)(As[p] + ci * 512 + lane * 8), 16, 0, 0);
      __builtin_amdgcn_global_load_lds(
          (GLOBAL_AS)(Bt + (size_t)(n0 + r) * K + k0 + gc),
          (LDS_AS)(Bs[p] + ci * 512 + lane * 8), 16, 0, 0);
    }
  };

  stage(0, 0);
  int p = 0;
  for(int k0 = 0; k0 < K; k0 += 64){
    __syncthreads();
    if(k0 + 64 < K) stage(p ^ 1, k0 + 64);
    #pragma unroll
    for(int kk = 0; kk < 2; kk++){
      s16x8 a[4], b[4];
      int ch = ((kk * 4 + quad) ^ (l15 & 7)) * 8;
      #pragma unroll
      for(int i = 0; i < 4; i++){
        a[i] = *(const s16x8*)&As[p][(wm + i*16 + l15) * 64 + ch];
        b[i] = *(const s16x8*)&Bs[p][(wn + i*16 + l15) * 64 + ch];
      }
      #pragma unroll
      for(int mt = 0; mt < 4; mt++)
        #pragma unroll
        for(int nt = 0; nt < 4; nt++)
          acc[mt][nt] = mfma16(a[mt], b[nt], acc[mt][nt]);
    }
    p ^= 1;
  }

  #pragma unroll
  for(int mt = 0; mt < 4; mt++){
    #pragma unroll
    for(int nt = 0; nt < 4; nt++){
      int n = n0 + wn + nt*16 + l15;
      float bv = bias[n];
      int which = n / EMB, rem = n - which * EMB;   // lane-uniform 'which'
      int h = rem >> 6, d = rem & 63;
      int mbase = m0 + wm + mt*16 + quad*4;
      int bb = mbase >> 10, sb = mbase & 1023;      // 4 consecutive m share bb
      size_t bh = (size_t)(bb * NH + h);
      if(which == 2){
        // V^T: 4 consecutive s -> one 8-B store
        ushort4 pk;
        pk.x = f2bf(acc[mt][nt][0] + bv);
        pk.y = f2bf(acc[mt][nt][1] + bv);
        pk.z = f2bf(acc[mt][nt][2] + bv);
        pk.w = f2bf(acc[mt][nt][3] + bv);
        *(ushort4*)&Vo[(bh * HD + d) * SS + sb] = pk;
      } else {
        u16* dst = (which == 0) ? Qo : Ko;
        #pragma unroll
        for(int r = 0; r < 4; r++)
          dst[(bh * SS + (sb + r)) * HD + d] = f2bf(acc[mt][nt][r] + bv);
      }
    }
  }
}

// ---------------- proj GEMM: 256x256 8-phase (r7 form — ~6.6us < 128² form) --
__global__ __launch_bounds__(512, 2) void proj_gemm_kernel(
    const u16* __restrict__ A, const u16* __restrict__ Bt,
    const float* __restrict__ bias, float* __restrict__ out){
  const int K = 768, NT = 12;
  __shared__ u16 As[2][256*64];
  __shared__ u16 Bs[2][256*64];
  int tid = threadIdx.x;

  int gx = gridDim.x;
  int nwg = gx * gridDim.y;
  int L = blockIdx.y * gx + blockIdx.x;
  int nl = (L & 7) * (nwg >> 3) + (L >> 3);
  int m0 = (nl / gx) * 256, n0 = (nl % gx) * 256;

  int w = tid >> 6, lane = tid & 63, quad = lane >> 4, l15 = lane & 15;
  int wm = (w >> 2) * 128, wn = (w & 3) * 64;
  int rr = lane >> 3;
  int cp = lane & 7;
  f32x4 acc[8][4] = {};

  auto stageQ = [&](int t, int q){
    int d = t & 1, k0 = t * 64;
    const u16* src = (q < 2) ? A : Bt;
    int base = (q < 2) ? m0 : n0;
    u16* dst = (q < 2) ? As[d] : Bs[d];
    int h = q & 1;
    #pragma unroll
    for(int it = 0; it < 2; ++it){
      int ci = h*16 + it*8 + w;
      int r  = ci * 8 + rr;
      int gc = (cp ^ (r & 7)) * 8;
      __builtin_amdgcn_global_load_lds(
          (GLOBAL_AS)(src + (size_t)(base + r) * K + k0 + gc),
          (LDS_AS)(dst + ci * 512 + lane * 8), 16, 0, 0);
    }
  };

  s16x8 a[8], b0[4], b1[4];
  auto dsA = [&](int d, int mh){
    #pragma unroll
    for(int kk = 0; kk < 2; ++kk){
      int ch = ((kk*4 + quad) ^ (l15 & 7)) * 8;
      #pragma unroll
      for(int i = 0; i < 4; ++i)
        a[kk*4+i] = *(const s16x8*)&As[d][(wm + (mh*4+i)*16 + l15) * 64 + ch];
    }
  };
  auto dsB = [&](int d, int nh, s16x8* bb){
    #pragma unroll
    for(int kk = 0; kk < 2; ++kk){
      int ch = ((kk*4 + quad) ^ (l15 & 7)) * 8;
      #pragma unroll
      for(int j = 0; j < 2; ++j)
        bb[kk*2+j] = *(const s16x8*)&Bs[d][(wn + (nh*2+j)*16 + l15) * 64 + ch];
    }
  };
  auto mfmaQ = [&](int mh, int nh, const s16x8* bb){
    __builtin_amdgcn_s_setprio(1);
    #pragma unroll
    for(int kk = 0; kk < 2; ++kk)
      #pragma unroll
      for(int i = 0; i < 4; ++i)
        #pragma unroll
        for(int j = 0; j < 2; ++j)
          acc[mh*4+i][nh*2+j] = mfma16(a[kk*4+i], bb[kk*2+j], acc[mh*4+i][nh*2+j]);
    __builtin_amdgcn_s_setprio(0);
  };

#define PHASE_SYNC() do{ \
    __builtin_amdgcn_s_barrier(); \
    asm volatile("s_waitcnt lgkmcnt(0)" ::: "memory"); \
    __builtin_amdgcn_sched_barrier(0); \
  }while(0)
#define PHASE_END() do{ \
    __builtin_amdgcn_s_barrier(); \
    __builtin_amdgcn_sched_barrier(0); \
  }while(0)

  stageQ(0,0); stageQ(0,1); stageQ(0,2); stageQ(0,3);
  stageQ(1,0);
  asm volatile("s_waitcnt vmcnt(2)" ::: "memory");
  __builtin_amdgcn_s_barrier();
  __builtin_amdgcn_sched_barrier(0);

  #pragma unroll
  for(int j = 0; j < NT/2; ++j){
    int t = 2*j;
    stageQ(t+1, 1);
    dsA(0, 0); dsB(0, 0, b0);
    PHASE_SYNC(); mfmaQ(0, 0, b0); PHASE_END();
    stageQ(t+1, 2);
    dsB(0, 1, b1);
    PHASE_SYNC(); mfmaQ(0, 1, b1); PHASE_END();
    stageQ(t+1, 3);
    dsA(0, 1);
    PHASE_SYNC(); mfmaQ(1, 0, b0); PHASE_END();
    if(t+2 < NT){ stageQ(t+2, 0); asm volatile("s_waitcnt vmcnt(2)" ::: "memory"); }
    else        { asm volatile("s_waitcnt vmcnt(0)" ::: "memory"); }
    PHASE_SYNC(); mfmaQ(1, 1, b1); PHASE_END();
    if(t+2 < NT) stageQ(t+2, 1);
    dsA(1, 0); dsB(1, 0, b0);
    PHASE_SYNC(); mfmaQ(0, 0, b0); PHASE_END();
    if(t+2 < NT) stageQ(t+2, 2);
    dsB(1, 1, b1);
    PHASE_SYNC(); mfmaQ(0, 1, b1); PHASE_END();
    if(t+2 < NT) stageQ(t+2, 3);
    dsA(1, 1);
    PHASE_SYNC(); mfmaQ(1, 0, b0); PHASE_END();
    if(t+3 < NT){ stageQ(t+3, 0); asm volatile("s_waitcnt vmcnt(2)" ::: "memory"); }
    else if(t+2 < NT){ asm volatile("s_waitcnt vmcnt(0)" ::: "memory"); }
    PHASE_SYNC(); mfmaQ(1, 1, b1); PHASE_END();
  }
#undef PHASE_SYNC
#undef PHASE_END

  #pragma unroll
  for(int mt = 0; mt < 8; ++mt){
    #pragma unroll
    for(int nt = 0; nt < 4; ++nt){
      int n = n0 + wn + nt*16 + l15;
      float bv = bias[n];
      #pragma unroll
      for(int r = 0; r < 4; ++r){
        int m = m0 + wm + mt*16 + quad*4 + r;
        out[(size_t)m * EMB + n] = acc[mt][nt][r] + bv;
      }
    }
  }
}

// ---------------- attention: block = (bh, 128 q-rows), double-buffered -------
// REVERTED byte-identical to the round-2/5 proven form. r9 post-mortem: the
// swapped-operand packed-P variant was +7us — LDS P-write path is LDS-BW/
// bank-bound (scalar b16 pattern is already bank-optimal: lane pairs merge
// into dwords, 32 distinct banks/instr); packing saved nothing and added
// VALU + 4-way conflicts.
__global__ __launch_bounds__(256) void attn_kernel(
    const u16* __restrict__ Qws, const u16* __restrict__ Kws,
    const u16* __restrict__ Vtws, u16* __restrict__ attn){
  __shared__ u16 Ks[2][64*64];                    // [key][d]   16 KB
  __shared__ u16 Vs[2][64*64];                    // [d][key]   16 KB
  __shared__ __align__(16) u16 Ps[4][2][16][76];  // [wave][m][q][key] 19 KB
  int tid = threadIdx.x;
  int w = tid >> 6, lane = tid & 63, quad = lane >> 4, l15 = lane & 15;
  int bh = blockIdx.x;                 // x=bh: all q-blocks of a bh -> same XCD
  int b = bh / NH, h = bh - b * NH;
  int q0 = blockIdx.y * 128 + w * 32;
  const u16* Qbase = Qws  + (size_t)bh * SS * HD;
  const u16* Kbase = Kws  + (size_t)bh * SS * HD;
  const u16* Vbase = Vtws + (size_t)bh * HD * SS;

  s16x8 aq[2][2];
  #pragma unroll
  for(int m = 0; m < 2; m++){
    int qrow = q0 + m*16 + l15;
    #pragma unroll
    for(int kk = 0; kk < 2; kk++)
      aq[m][kk] = *(const s16x8*)(Qbase + (size_t)qrow * HD + kk*32 + quad*8);
  }

  f32x4 o[2][4] = {};
  float psum[2][4] = {};
  const float C1 = 0.125f * 1.44269504f;
  const float C0 = -30.0f * 1.44269504f;

  int krr = lane >> 3, kcp = lane & 7;   // staging decode: 8 rows x 8 chunks

  auto stageKV = [&](int p, int kt){
    #pragma unroll
    for(int it = 0; it < 2; ++it){
      int ins = it * 4 + w;              // 0..7
      int r   = ins * 8 + krr;           // 0..63
      int gck = (kcp ^ (r & 7)) * 8;
      __builtin_amdgcn_global_load_lds(
          (GLOBAL_AS)(Kbase + (size_t)(kt*64 + r) * HD + gck),
          (LDS_AS)(Ks[p] + ins * 512 + lane * 8), 16, 0, 0);
      __builtin_amdgcn_global_load_lds(
          (GLOBAL_AS)(Vbase + (size_t)r * SS + kt*64 + gck),
          (LDS_AS)(Vs[p] + ins * 512 + lane * 8), 16, 0, 0);
    }
  };

  stageKV(0, 0);
  int p = 0;
  for(int kt = 0; kt < 16; ++kt){        // 64 keys per iteration
    __syncthreads();                     // drains stage(p); publishes buf p
    if(kt < 15) stageKV(p ^ 1, kt + 1);  // prefetch overlaps compute

    // scores + exp + P  (4 key-tiles of 16)
    #pragma unroll
    for(int nt = 0; nt < 4; ++nt){
      s16x8 bk[2];
      #pragma unroll
      for(int kk = 0; kk < 2; kk++){
        int ch = ((kk*4 + quad) ^ (l15 & 7)) * 8;
        bk[kk] = *(const s16x8*)&Ks[p][(nt*16 + l15) * 64 + ch];
      }
      #pragma unroll
      for(int m = 0; m < 2; m++){
        f32x4 z = {};
        z = mfma16(aq[m][0], bk[0], z);
        z = mfma16(aq[m][1], bk[1], z);
        #pragma unroll
        for(int r = 0; r < 4; r++){
          float pv = EXP2(z[r] * C1 + C0);
          psum[m][r] += pv;
          Ps[w][m][quad*4 + r][nt*16 + l15] = f2bf_trunc(pv);
        }
      }
    }
    // PV: o(2x16x64) += P(2x16x64) @ V(64x64)
    #pragma unroll
    for(int k4 = 0; k4 < 2; k4++){
      s16x8 pa[2];
      #pragma unroll
      for(int m = 0; m < 2; m++)
        pa[m] = *(const s16x8*)&Ps[w][m][l15][k4*32 + quad*8];
      #pragma unroll
      for(int nt = 0; nt < 4; nt++){
        int ch = ((k4*4 + quad) ^ (l15 & 7)) * 8;
        s16x8 vb = *(const s16x8*)&Vs[p][(nt*16 + l15) * 64 + ch];
        #pragma unroll
        for(int m = 0; m < 2; m++)
          o[m][nt] = mfma16(pa[m], vb, o[m][nt]);
      }
    }
    p ^= 1;
  }

  // epilogue: out[b, s, h*64+d] = o / rowsum
  #pragma unroll
  for(int m = 0; m < 2; m++){
    #pragma unroll
    for(int r = 0; r < 4; r++){
      float s = psum[m][r];
      s += __shfl_xor(s, 1, 64);
      s += __shfl_xor(s, 2, 64);
      s += __shfl_xor(s, 4, 64);
      s += __shfl_xor(s, 8, 64);
      float inv = 1.0f / s;
      int srow = q0 + m*16 + quad*4 + r;
      size_t base = ((size_t)(b * SS + srow)) * EMB + h * HD;
      #pragma unroll
      for(int nt = 0; nt < 4; nt++)
        attn[base + nt*16 + l15] = f2bf(o[m][nt][r] * inv);
    }
  }
}

extern "C" void kernel_launch(void* const* d_in, const int* in_sizes, int n_in,
                              void* d_out, int out_size, void* d_ws, size_t ws_size,
                              hipStream_t stream){
  const float* x      = (const float*)d_in[0];
  const float* qkv_w  = (const float*)d_in[1];
  const float* qkv_b  = (const float*)d_in[2];
  const float* proj_w = (const float*)d_in[3];
  const float* proj_b = (const float*)d_in[4];

  char* ws = (char*)d_ws;
  u16* qkv_wT  = (u16*)ws; ws += (size_t)NQKV * EMB * 2;   // [2304,768] bf16
  u16* proj_wT = (u16*)ws; ws += (size_t)EMB * EMB * 2;    // [768,768] bf16
  u16* x_bf = (u16*)ws; ws += QSZ * 2;   // [16384,768] bf16; reused as attn out
  u16* Qws  = (u16*)ws; ws += QSZ * 2;                     // [bh,S,D]
  u16* Kws  = (u16*)ws; ws += QSZ * 2;                     // [bh,S,D]
  u16* Vtws = (u16*)ws; ws += QSZ * 2;                     // [bh,D,S]
  u16* attn = x_bf;

  prep_kernel<<<NBA + NBB + NBC, 256, 0, stream>>>(
      (const float4*)x, (ushort4*)x_bf, qkv_w, qkv_wT, proj_w, proj_wT);
  qkv_gemm_kernel<<<dim3(NQKV/128, MTOK/128), 256, 0, stream>>>(
      x_bf, qkv_wT, qkv_b, Qws, Kws, Vtws);
  attn_kernel<<<dim3(BB*NH, SS/128), 256, 0, stream>>>(Qws, Kws, Vtws, attn);
  proj_gemm_kernel<<<dim3(EMB/256, MTOK/256), 512, 0, stream>>>(
      attn, proj_wT, proj_b, (float*)d_out);
}

// Round 11
// 287.076 us; speedup vs baseline: 1.1018x; 1.0262x over previous
//
#include <hip/hip_runtime.h>
#include <hip/hip_bf16.h>

typedef unsigned short u16;
typedef unsigned int u32;
typedef short s16x8 __attribute__((ext_vector_type(8)));
typedef float f32x4 __attribute__((ext_vector_type(4)));

#define EMB 768
#define NH 12
#define HD 64
#define BB 16
#define SS 1024
#define MTOK (BB*SS)      // 16384
#define NQKV (3*EMB)      // 2304
#define QSZ ((size_t)BB*NH*SS*HD)   // 12,582,912 elements

#define GLOBAL_AS const __attribute__((address_space(1))) void*
#define LDS_AS __attribute__((address_space(3))) void*

#if __has_builtin(__builtin_amdgcn_exp2f)
#define EXP2(x) __builtin_amdgcn_exp2f(x)
#else
#define EXP2(x) exp2f(x)
#endif

__device__ __forceinline__ u16 f2bf(float f){          // RNE
  unsigned u = __float_as_uint(f);
  u += 0x7FFFu + ((u >> 16) & 1u);
  return (u16)(u >> 16);
}
__device__ __forceinline__ u16 f2bf_trunc(float f){    // truncate (P only)
  return (u16)(__float_as_uint(f) >> 16);
}
__device__ __forceinline__ f32x4 mfma16(s16x8 a, s16x8 b, f32x4 c){
  return __builtin_amdgcn_mfma_f32_16x16x32_bf16(a, b, c, 0, 0, 0);
}

// ---------------- fused prep: x-convert + both weight transposes ------------
#define NBA 12288   // (QSZ/4)/256 exactly
#define NBB 1728    // (NQKV/32)*(EMB/32) = 72*24
#define NBC 576     // (EMB/32)*(EMB/32)  = 24*24

__device__ __forceinline__ void transpose_body(
    u16 (*tile)[33], const float* __restrict__ in, u16* __restrict__ out,
    int R, int C, int bxi, int byi){
  int bx = bxi * 32, by = byi * 32;
  int tx = threadIdx.x & 31, ty = threadIdx.x >> 5;
  #pragma unroll
  for(int i = 0; i < 32; i += 8)
    tile[ty + i][tx] = f2bf(in[(size_t)(by + ty + i) * C + bx + tx]);
  __syncthreads();
  #pragma unroll
  for(int i = 0; i < 32; i += 8)
    out[(size_t)(bx + ty + i) * R + by + tx] = tile[tx][ty + i];
}

__global__ __launch_bounds__(256) void prep_kernel(
    const float4* __restrict__ x4, ushort4* __restrict__ xb4,
    const float* __restrict__ qkv_w, u16* __restrict__ qkv_wT,
    const float* __restrict__ proj_w, u16* __restrict__ proj_wT){
  __shared__ u16 tile[32][33];
  int bid = blockIdx.x;
  if(bid < NBA){
    int i = bid * 256 + threadIdx.x;          // NBA*256 == QSZ/4 exactly
    float4 f = x4[i];
    ushort4 o;
    o.x = f2bf(f.x); o.y = f2bf(f.y); o.z = f2bf(f.z); o.w = f2bf(f.w);
    xb4[i] = o;
  } else if(bid < NBA + NBB){
    int bi = bid - NBA;                        // qkv_w [768,2304] -> [2304,768]
    transpose_body(tile, qkv_w, qkv_wT, EMB, NQKV, bi % (NQKV/32), bi / (NQKV/32));
  } else {
    int bi = bid - NBA - NBB;                  // proj_w [768,768] -> [768,768]
    transpose_body(tile, proj_w, proj_wT, EMB, EMB, bi % (EMB/32), bi / (EMB/32));
  }
}

// ---------------- qkv GEMM: 128x128, double-buffered + packed V^T stores -----
// r10: V^T dwordx2 pack dropped qkv from 103.4 to <93 us (out of top-5).
// UNCHANGED this round.
__global__ __launch_bounds__(256) void qkv_gemm_kernel(
    const u16* __restrict__ A, const u16* __restrict__ Bt,
    const float* __restrict__ bias,
    u16* __restrict__ Qo, u16* __restrict__ Ko, u16* __restrict__ Vo){
  const int K = 768;
  __shared__ u16 As[2][128*64];
  __shared__ u16 Bs[2][128*64];
  int tid = threadIdx.x;

  // T1: bijective XCD-chunked swizzle (nwg % 8 == 0: 2304)
  int gx = gridDim.x;
  int nwg = gx * gridDim.y;
  int L = blockIdx.y * gx + blockIdx.x;
  int nl = (L & 7) * (nwg >> 3) + (L >> 3);
  int m0 = (nl / gx) * 128, n0 = (nl % gx) * 128;

  int w = tid >> 6, lane = tid & 63, quad = lane >> 4, l15 = lane & 15;
  int wm = (w >> 1) * 64, wn = (w & 1) * 64;
  int rr = lane >> 3;          // row within a 1KB chunk-issue (0..7)
  int cp = lane & 7;           // 16B chunk position within row
  f32x4 acc[4][4] = {};

  auto stage = [&](int p, int k0){
    #pragma unroll
    for(int it = 0; it < 4; ++it){
      int ci = it * 4 + w;
      int r  = ci * 8 + rr;
      int gc = (cp ^ (r & 7)) * 8;
      __builtin_amdgcn_global_load_lds(
          (GLOBAL_AS)(A + (size_t)(m0 + r) * K + k0 + gc),
          (LDS_AS)(As[p] + ci * 512 + lane * 8), 16, 0, 0);
      __builtin_amdgcn_global_load_lds(
          (GLOBAL_AS)(Bt + (size_t)(n0 + r) * K + k0 + gc),
          (LDS_AS)(Bs[p] + ci * 512 + lane * 8), 16, 0, 0);
    }
  };

  stage(0, 0);
  int p = 0;
  for(int k0 = 0; k0 < K; k0 += 64){
    __syncthreads();
    if(k0 + 64 < K) stage(p ^ 1, k0 + 64);
    #pragma unroll
    for(int kk = 0; kk < 2; kk++){
      s16x8 a[4], b[4];
      int ch = ((kk * 4 + quad) ^ (l15 & 7)) * 8;
      #pragma unroll
      for(int i = 0; i < 4; i++){
        a[i] = *(const s16x8*)&As[p][(wm + i*16 + l15) * 64 + ch];
        b[i] = *(const s16x8*)&Bs[p][(wn + i*16 + l15) * 64 + ch];
      }
      #pragma unroll
      for(int mt = 0; mt < 4; mt++)
        #pragma unroll
        for(int nt = 0; nt < 4; nt++)
          acc[mt][nt] = mfma16(a[mt], b[nt], acc[mt][nt]);
    }
    p ^= 1;
  }

  #pragma unroll
  for(int mt = 0; mt < 4; mt++){
    #pragma unroll
    for(int nt = 0; nt < 4; nt++){
      int n = n0 + wn + nt*16 + l15;
      float bv = bias[n];
      int which = n / EMB, rem = n - which * EMB;   // lane-uniform 'which'
      int h = rem >> 6, d = rem & 63;
      int mbase = m0 + wm + mt*16 + quad*4;
      int bb = mbase >> 10, sb = mbase & 1023;      // 4 consecutive m share bb
      size_t bh = (size_t)(bb * NH + h);
      if(which == 2){
        // V^T: 4 consecutive s -> one 8-B store
        ushort4 pk;
        pk.x = f2bf(acc[mt][nt][0] + bv);
        pk.y = f2bf(acc[mt][nt][1] + bv);
        pk.z = f2bf(acc[mt][nt][2] + bv);
        pk.w = f2bf(acc[mt][nt][3] + bv);
        *(ushort4*)&Vo[(bh * HD + d) * SS + sb] = pk;
      } else {
        u16* dst = (which == 0) ? Qo : Ko;
        #pragma unroll
        for(int r = 0; r < 4; r++)
          dst[(bh * SS + (sb + r)) * HD + d] = f2bf(acc[mt][nt][r] + bv);
      }
    }
  }
}

// ---------------- proj GEMM: 256x256 8-phase (r7 form) -----------------------
__global__ __launch_bounds__(512, 2) void proj_gemm_kernel(
    const u16* __restrict__ A, const u16* __restrict__ Bt,
    const float* __restrict__ bias, float* __restrict__ out){
  const int K = 768, NT = 12;
  __shared__ u16 As[2][256*64];
  __shared__ u16 Bs[2][256*64];
  int tid = threadIdx.x;

  int gx = gridDim.x;
  int nwg = gx * gridDim.y;
  int L = blockIdx.y * gx + blockIdx.x;
  int nl = (L & 7) * (nwg >> 3) + (L >> 3);
  int m0 = (nl / gx) * 256, n0 = (nl % gx) * 256;

  int w = tid >> 6, lane = tid & 63, quad = lane >> 4, l15 = lane & 15;
  int wm = (w >> 2) * 128, wn = (w & 3) * 64;
  int rr = lane >> 3;
  int cp = lane & 7;
  f32x4 acc[8][4] = {};

  auto stageQ = [&](int t, int q){
    int d = t & 1, k0 = t * 64;
    const u16* src = (q < 2) ? A : Bt;
    int base = (q < 2) ? m0 : n0;
    u16* dst = (q < 2) ? As[d] : Bs[d];
    int h = q & 1;
    #pragma unroll
    for(int it = 0; it < 2; ++it){
      int ci = h*16 + it*8 + w;
      int r  = ci * 8 + rr;
      int gc = (cp ^ (r & 7)) * 8;
      __builtin_amdgcn_global_load_lds(
          (GLOBAL_AS)(src + (size_t)(base + r) * K + k0 + gc),
          (LDS_AS)(dst + ci * 512 + lane * 8), 16, 0, 0);
    }
  };

  s16x8 a[8], b0[4], b1[4];
  auto dsA = [&](int d, int mh){
    #pragma unroll
    for(int kk = 0; kk < 2; ++kk){
      int ch = ((kk*4 + quad) ^ (l15 & 7)) * 8;
      #pragma unroll
      for(int i = 0; i < 4; ++i)
        a[kk*4+i] = *(const s16x8*)&As[d][(wm + (mh*4+i)*16 + l15) * 64 + ch];
    }
  };
  auto dsB = [&](int d, int nh, s16x8* bb){
    #pragma unroll
    for(int kk = 0; kk < 2; ++kk){
      int ch = ((kk*4 + quad) ^ (l15 & 7)) * 8;
      #pragma unroll
      for(int j = 0; j < 2; ++j)
        bb[kk*2+j] = *(const s16x8*)&Bs[d][(wn + (nh*2+j)*16 + l15) * 64 + ch];
    }
  };
  auto mfmaQ = [&](int mh, int nh, const s16x8* bb){
    __builtin_amdgcn_s_setprio(1);
    #pragma unroll
    for(int kk = 0; kk < 2; ++kk)
      #pragma unroll
      for(int i = 0; i < 4; ++i)
        #pragma unroll
        for(int j = 0; j < 2; ++j)
          acc[mh*4+i][nh*2+j] = mfma16(a[kk*4+i], bb[kk*2+j], acc[mh*4+i][nh*2+j]);
    __builtin_amdgcn_s_setprio(0);
  };

#define PHASE_SYNC() do{ \
    __builtin_amdgcn_s_barrier(); \
    asm volatile("s_waitcnt lgkmcnt(0)" ::: "memory"); \
    __builtin_amdgcn_sched_barrier(0); \
  }while(0)
#define PHASE_END() do{ \
    __builtin_amdgcn_s_barrier(); \
    __builtin_amdgcn_sched_barrier(0); \
  }while(0)

  stageQ(0,0); stageQ(0,1); stageQ(0,2); stageQ(0,3);
  stageQ(1,0);
  asm volatile("s_waitcnt vmcnt(2)" ::: "memory");
  __builtin_amdgcn_s_barrier();
  __builtin_amdgcn_sched_barrier(0);

  #pragma unroll
  for(int j = 0; j < NT/2; ++j){
    int t = 2*j;
    stageQ(t+1, 1);
    dsA(0, 0); dsB(0, 0, b0);
    PHASE_SYNC(); mfmaQ(0, 0, b0); PHASE_END();
    stageQ(t+1, 2);
    dsB(0, 1, b1);
    PHASE_SYNC(); mfmaQ(0, 1, b1); PHASE_END();
    stageQ(t+1, 3);
    dsA(0, 1);
    PHASE_SYNC(); mfmaQ(1, 0, b0); PHASE_END();
    if(t+2 < NT){ stageQ(t+2, 0); asm volatile("s_waitcnt vmcnt(2)" ::: "memory"); }
    else        { asm volatile("s_waitcnt vmcnt(0)" ::: "memory"); }
    PHASE_SYNC(); mfmaQ(1, 1, b1); PHASE_END();
    if(t+2 < NT) stageQ(t+2, 1);
    dsA(1, 0); dsB(1, 0, b0);
    PHASE_SYNC(); mfmaQ(0, 0, b0); PHASE_END();
    if(t+2 < NT) stageQ(t+2, 2);
    dsB(1, 1, b1);
    PHASE_SYNC(); mfmaQ(0, 1, b1); PHASE_END();
    if(t+2 < NT) stageQ(t+2, 3);
    dsA(1, 1);
    PHASE_SYNC(); mfmaQ(1, 0, b0); PHASE_END();
    if(t+3 < NT){ stageQ(t+3, 0); asm volatile("s_waitcnt vmcnt(2)" ::: "memory"); }
    else if(t+2 < NT){ asm volatile("s_waitcnt vmcnt(0)" ::: "memory"); }
    PHASE_SYNC(); mfmaQ(1, 1, b1); PHASE_END();
  }
#undef PHASE_SYNC
#undef PHASE_END

  #pragma unroll
  for(int mt = 0; mt < 8; ++mt){
    #pragma unroll
    for(int nt = 0; nt < 4; ++nt){
      int n = n0 + wn + nt*16 + l15;
      float bv = bias[n];
      #pragma unroll
      for(int r = 0; r < 4; ++r){
        int m = m0 + wm + mt*16 + quad*4 + r;
        out[(size_t)m * EMB + n] = acc[mt][nt][r] + bv;
      }
    }
  }
}

// ---------------- attention: 512-thread blocks (8 waves, 256 q-rows) ---------
// ROUND-11 DELTA: attn was TLP-starved (93us = ~4660cyc/kt/block vs ~800cyc
// of throughput work; 2 waves/SIMD can't hide the staging latency+barrier).
// 8 waves share one K/V staging (per-thread staging halves: 2 loads/kt) and
// LDS = 16+16+38.9(Ps[8]) = 71.7KB -> 2 blocks/CU = 16 waves/CU (2x TLP).
// Grid 192 x 4 (1.5 residency rounds vs 3). Per-wave compute code identical.
__global__ __launch_bounds__(512) void attn_kernel(
    const u16* __restrict__ Qws, const u16* __restrict__ Kws,
    const u16* __restrict__ Vtws, u16* __restrict__ attn){
  __shared__ u16 Ks[2][64*64];                    // [key][d]   16 KB
  __shared__ u16 Vs[2][64*64];                    // [d][key]   16 KB
  __shared__ __align__(16) u16 Ps[8][2][16][76];  // [wave][m][q][key] 38.9 KB
  int tid = threadIdx.x;
  int w = tid >> 6, lane = tid & 63, quad = lane >> 4, l15 = lane & 15;
  int bh = blockIdx.x;                 // x=bh: all q-blocks of a bh -> same XCD
  int b = bh / NH, h = bh - b * NH;
  int q0 = blockIdx.y * 256 + w * 32;
  const u16* Qbase = Qws  + (size_t)bh * SS * HD;
  const u16* Kbase = Kws  + (size_t)bh * SS * HD;
  const u16* Vbase = Vtws + (size_t)bh * HD * SS;

  s16x8 aq[2][2];
  #pragma unroll
  for(int m = 0; m < 2; m++){
    int qrow = q0 + m*16 + l15;
    #pragma unroll
    for(int kk = 0; kk < 2; kk++)
      aq[m][kk] = *(const s16x8*)(Qbase + (size_t)qrow * HD + kk*32 + quad*8);
  }

  f32x4 o[2][4] = {};
  float psum[2][4] = {};
  const float C1 = 0.125f * 1.44269504f;
  const float C0 = -30.0f * 1.44269504f;

  int krr = lane >> 3, kcp = lane & 7;   // staging decode: 8 rows x 8 chunks

  auto stageKV = [&](int p, int kt){
    int ins = w;                         // 8 waves cover 8 row-groups
    int r   = ins * 8 + krr;             // 0..63
    int gck = (kcp ^ (r & 7)) * 8;
    __builtin_amdgcn_global_load_lds(
        (GLOBAL_AS)(Kbase + (size_t)(kt*64 + r) * HD + gck),
        (LDS_AS)(Ks[p] + ins * 512 + lane * 8), 16, 0, 0);
    __builtin_amdgcn_global_load_lds(
        (GLOBAL_AS)(Vbase + (size_t)r * SS + kt*64 + gck),
        (LDS_AS)(Vs[p] + ins * 512 + lane * 8), 16, 0, 0);
  };

  stageKV(0, 0);
  int p = 0;
  for(int kt = 0; kt < 16; ++kt){        // 64 keys per iteration
    __syncthreads();                     // drains stage(p); publishes buf p
    if(kt < 15) stageKV(p ^ 1, kt + 1);  // prefetch overlaps compute

    // scores + exp + P  (4 key-tiles of 16)
    #pragma unroll
    for(int nt = 0; nt < 4; ++nt){
      s16x8 bk[2];
      #pragma unroll
      for(int kk = 0; kk < 2; kk++){
        int ch = ((kk*4 + quad) ^ (l15 & 7)) * 8;
        bk[kk] = *(const s16x8*)&Ks[p][(nt*16 + l15) * 64 + ch];
      }
      #pragma unroll
      for(int m = 0; m < 2; m++){
        f32x4 z = {};
        z = mfma16(aq[m][0], bk[0], z);
        z = mfma16(aq[m][1], bk[1], z);
        #pragma unroll
        for(int r = 0; r < 4; r++){
          float pv = EXP2(z[r] * C1 + C0);
          psum[m][r] += pv;
          Ps[w][m][quad*4 + r][nt*16 + l15] = f2bf_trunc(pv);
        }
      }
    }
    // PV: o(2x16x64) += P(2x16x64) @ V(64x64)
    #pragma unroll
    for(int k4 = 0; k4 < 2; k4++){
      s16x8 pa[2];
      #pragma unroll
      for(int m = 0; m < 2; m++)
        pa[m] = *(const s16x8*)&Ps[w][m][l15][k4*32 + quad*8];
      #pragma unroll
      for(int nt = 0; nt < 4; nt++){
        int ch = ((k4*4 + quad) ^ (l15 & 7)) * 8;
        s16x8 vb = *(const s16x8*)&Vs[p][(nt*16 + l15) * 64 + ch];
        #pragma unroll
        for(int m = 0; m < 2; m++)
          o[m][nt] = mfma16(pa[m], vb, o[m][nt]);
      }
    }
    p ^= 1;
  }

  // epilogue: out[b, s, h*64+d] = o / rowsum
  #pragma unroll
  for(int m = 0; m < 2; m++){
    #pragma unroll
    for(int r = 0; r < 4; r++){
      float s = psum[m][r];
      s += __shfl_xor(s, 1, 64);
      s += __shfl_xor(s, 2, 64);
      s += __shfl_xor(s, 4, 64);
      s += __shfl_xor(s, 8, 64);
      float inv = 1.0f / s;
      int srow = q0 + m*16 + quad*4 + r;
      size_t base = ((size_t)(b * SS + srow)) * EMB + h * HD;
      #pragma unroll
      for(int nt = 0; nt < 4; nt++)
        attn[base + nt*16 + l15] = f2bf(o[m][nt][r] * inv);
    }
  }
}

extern "C" void kernel_launch(void* const* d_in, const int* in_sizes, int n_in,
                              void* d_out, int out_size, void* d_ws, size_t ws_size,
                              hipStream_t stream){
  const float* x      = (const float*)d_in[0];
  const float* qkv_w  = (const float*)d_in[1];
  const float* qkv_b  = (const float*)d_in[2];
  const float* proj_w = (const float*)d_in[3];
  const float* proj_b = (const float*)d_in[4];

  char* ws = (char*)d_ws;
  u16* qkv_wT  = (u16*)ws; ws += (size_t)NQKV * EMB * 2;   // [2304,768] bf16
  u16* proj_wT = (u16*)ws; ws += (size_t)EMB * EMB * 2;    // [768,768] bf16
  u16* x_bf = (u16*)ws; ws += QSZ * 2;   // [16384,768] bf16; reused as attn out
  u16* Qws  = (u16*)ws; ws += QSZ * 2;                     // [bh,S,D]
  u16* Kws  = (u16*)ws; ws += QSZ * 2;                     // [bh,S,D]
  u16* Vtws = (u16*)ws; ws += QSZ * 2;                     // [bh,D,S]
  u16* attn = x_bf;

  prep_kernel<<<NBA + NBB + NBC, 256, 0, stream>>>(
      (const float4*)x, (ushort4*)x_bf, qkv_w, qkv_wT, proj_w, proj_wT);
  qkv_gemm_kernel<<<dim3(NQKV/128, MTOK/128), 256, 0, stream>>>(
      x_bf, qkv_wT, qkv_b, Qws, Kws, Vtws);
  attn_kernel<<<dim3(BB*NH, SS/256), 512, 0, stream>>>(Qws, Kws, Vtws, attn);
  proj_gemm_kernel<<<dim3(EMB/256, MTOK/256), 512, 0, stream>>>(
      attn, proj_wT, proj_b, (float*)d_out);
}

// Round 12
// 277.039 us; speedup vs baseline: 1.1417x; 1.0362x over previous
//
#include <hip/hip_runtime.h>
#include <hip/hip_bf16.h>

typedef unsigned short u16;
typedef unsigned int u32;
typedef short s16x8 __attribute__((ext_vector_type(8)));
typedef float f32x4 __attribute__((ext_vector_type(4)));

#define EMB 768
#define NH 12
#define HD 64
#define BB 16
#define SS 1024
#define MTOK (BB*SS)      // 16384
#define NQKV (3*EMB)      // 2304
#define QSZ ((size_t)BB*NH*SS*HD)   // 12,582,912 elements

#define GLOBAL_AS const __attribute__((address_space(1))) void*
#define LDS_AS __attribute__((address_space(3))) void*

#if __has_builtin(__builtin_amdgcn_exp2f)
#define EXP2(x) __builtin_amdgcn_exp2f(x)
#else
#define EXP2(x) exp2f(x)
#endif

__device__ __forceinline__ u16 f2bf(float f){          // RNE
  unsigned u = __float_as_uint(f);
  u += 0x7FFFu + ((u >> 16) & 1u);
  return (u16)(u >> 16);
}
__device__ __forceinline__ u16 f2bf_trunc(float f){    // truncate (P only)
  return (u16)(__float_as_uint(f) >> 16);
}
__device__ __forceinline__ f32x4 mfma16(s16x8 a, s16x8 b, f32x4 c){
  return __builtin_amdgcn_mfma_f32_16x16x32_bf16(a, b, c, 0, 0, 0);
}

// ---------------- fused prep: x-convert + both weight transposes ------------
#define NBA 12288   // (QSZ/4)/256 exactly
#define NBB 1728    // (NQKV/32)*(EMB/32) = 72*24
#define NBC 576     // (EMB/32)*(EMB/32)  = 24*24

__device__ __forceinline__ void transpose_body(
    u16 (*tile)[33], const float* __restrict__ in, u16* __restrict__ out,
    int R, int C, int bxi, int byi){
  int bx = bxi * 32, by = byi * 32;
  int tx = threadIdx.x & 31, ty = threadIdx.x >> 5;
  #pragma unroll
  for(int i = 0; i < 32; i += 8)
    tile[ty + i][tx] = f2bf(in[(size_t)(by + ty + i) * C + bx + tx]);
  __syncthreads();
  #pragma unroll
  for(int i = 0; i < 32; i += 8)
    out[(size_t)(bx + ty + i) * R + by + tx] = tile[tx][ty + i];
}

__global__ __launch_bounds__(256) void prep_kernel(
    const float4* __restrict__ x4, ushort4* __restrict__ xb4,
    const float* __restrict__ qkv_w, u16* __restrict__ qkv_wT,
    const float* __restrict__ proj_w, u16* __restrict__ proj_wT){
  __shared__ u16 tile[32][33];
  int bid = blockIdx.x;
  if(bid < NBA){
    int i = bid * 256 + threadIdx.x;          // NBA*256 == QSZ/4 exactly
    float4 f = x4[i];
    ushort4 o;
    o.x = f2bf(f.x); o.y = f2bf(f.y); o.z = f2bf(f.z); o.w = f2bf(f.w);
    xb4[i] = o;
  } else if(bid < NBA + NBB){
    int bi = bid - NBA;                        // qkv_w [768,2304] -> [2304,768]
    transpose_body(tile, qkv_w, qkv_wT, EMB, NQKV, bi % (NQKV/32), bi / (NQKV/32));
  } else {
    int bi = bid - NBA - NBB;                  // proj_w [768,768] -> [768,768]
    transpose_body(tile, proj_w, proj_wT, EMB, EMB, bi % (EMB/32), bi / (EMB/32));
  }
}

// ---------------- qkv GEMM: 128x128, double-buffered -------------------------
// ROUND-12 DELTA: Q/K epilogue coalescing via LDS transpose. r10's V^T pack
// proved the epilogue was store-bound (-18us). Q/K blocks (which<2 is
// block-uniform: every 128-wide n-tile lies in one third) still issued 64
// scalar b16 stores/thread (4x32B segments each). Now: staging LDS (dead
// after K-loop) is reused as ep[128][136] (pad 8 -> 2-way-free writes,
// 4-bank row shift on reads); barrier -> acc+bias -> ep -> barrier ->
// 8 x b128 read + 8 x global dwordx4/thread (8x128B segments per wave).
// V path unchanged (packed dwordx2). Main loop byte-identical.
__global__ __launch_bounds__(256) void qkv_gemm_kernel(
    const u16* __restrict__ A, const u16* __restrict__ Bt,
    const float* __restrict__ bias,
    u16* __restrict__ Qo, u16* __restrict__ Ko, u16* __restrict__ Vo){
  const int K = 768;
  __shared__ u16 SH[4][128*64];          // [0..1]=As, [2..3]=Bs; 64 KB
  u16 (*As)[128*64] = &SH[0];
  u16 (*Bs)[128*64] = &SH[2];
  int tid = threadIdx.x;

  // T1: bijective XCD-chunked swizzle (nwg % 8 == 0: 2304)
  int gx = gridDim.x;
  int nwg = gx * gridDim.y;
  int L = blockIdx.y * gx + blockIdx.x;
  int nl = (L & 7) * (nwg >> 3) + (L >> 3);
  int m0 = (nl / gx) * 128, n0 = (nl % gx) * 128;

  int w = tid >> 6, lane = tid & 63, quad = lane >> 4, l15 = lane & 15;
  int wm = (w >> 1) * 64, wn = (w & 1) * 64;
  int rr = lane >> 3;          // row within a 1KB chunk-issue (0..7)
  int cp = lane & 7;           // 16B chunk position within row
  f32x4 acc[4][4] = {};

  auto stage = [&](int p, int k0){
    #pragma unroll
    for(int it = 0; it < 4; ++it){
      int ci = it * 4 + w;
      int r  = ci * 8 + rr;
      int gc = (cp ^ (r & 7)) * 8;
      __builtin_amdgcn_global_load_lds(
          (GLOBAL_AS)(A + (size_t)(m0 + r) * K + k0 + gc),
          (LDS_AS)(As[p] + ci * 512 + lane * 8), 16, 0, 0);
      __builtin_amdgcn_global_load_lds(
          (GLOBAL_AS)(Bt + (size_t)(n0 + r) * K + k0 + gc),
          (LDS_AS)(Bs[p] + ci * 512 + lane * 8), 16, 0, 0);
    }
  };

  stage(0, 0);
  int p = 0;
  for(int k0 = 0; k0 < K; k0 += 64){
    __syncthreads();
    if(k0 + 64 < K) stage(p ^ 1, k0 + 64);
    #pragma unroll
    for(int kk = 0; kk < 2; kk++){
      s16x8 a[4], b[4];
      int ch = ((kk * 4 + quad) ^ (l15 & 7)) * 8;
      #pragma unroll
      for(int i = 0; i < 4; i++){
        a[i] = *(const s16x8*)&As[p][(wm + i*16 + l15) * 64 + ch];
        b[i] = *(const s16x8*)&Bs[p][(wn + i*16 + l15) * 64 + ch];
      }
      #pragma unroll
      for(int mt = 0; mt < 4; mt++)
        #pragma unroll
        for(int nt = 0; nt < 4; nt++)
          acc[mt][nt] = mfma16(a[mt], b[nt], acc[mt][nt]);
    }
    p ^= 1;
  }

  int which = (n0 + wn) / EMB;           // block-uniform (128-tile in one third)
  if(which == 2){
    // V^T: 4 consecutive s -> one 8-B store (r10 proven path)
    #pragma unroll
    for(int mt = 0; mt < 4; mt++){
      #pragma unroll
      for(int nt = 0; nt < 4; nt++){
        int n = n0 + wn + nt*16 + l15;
        float bv = bias[n];
        int rem = n - 2 * EMB;
        int h = rem >> 6, d = rem & 63;
        int mbase = m0 + wm + mt*16 + quad*4;
        int bb = mbase >> 10, sb = mbase & 1023;
        size_t bh = (size_t)(bb * NH + h);
        ushort4 pk;
        pk.x = f2bf(acc[mt][nt][0] + bv);
        pk.y = f2bf(acc[mt][nt][1] + bv);
        pk.z = f2bf(acc[mt][nt][2] + bv);
        pk.w = f2bf(acc[mt][nt][3] + bv);
        *(ushort4*)&Vo[(bh * HD + d) * SS + sb] = pk;
      }
    }
  } else {
    // Q/K: LDS transpose epilogue -> fully coalesced dwordx4 row stores
    u16* ep = &SH[0][0];                 // [128][136] u16 = 34 KB (LDS dead)
    __syncthreads();                     // all waves done reading staging LDS
    #pragma unroll
    for(int mt = 0; mt < 4; mt++){
      #pragma unroll
      for(int nt = 0; nt < 4; nt++){
        int n = n0 + wn + nt*16 + l15;
        float bv = bias[n];
        int row0 = wm + mt*16 + quad*4;
        #pragma unroll
        for(int r = 0; r < 4; r++)
          ep[(row0 + r) * 136 + wn + nt*16 + l15] = f2bf(acc[mt][nt][r] + bv);
      }
    }
    __syncthreads();
    u16* dst = (which == 0) ? Qo : Ko;
    int nb = n0 - which * EMB;           // block n-offset within its third
    #pragma unroll
    for(int pass = 0; pass < 8; ++pass){
      int c = pass * 256 + tid;          // 2048 chunks of 8 u16
      int row = c >> 4, chunk = c & 15;
      s16x8 v = *(const s16x8*)&ep[row * 136 + chunk * 8];
      int m = m0 + row;
      int bb = m >> 10, ss = m & 1023;
      int rem = nb + chunk * 8;
      int h = rem >> 6, d = rem & 63;
      size_t bh = (size_t)(bb * NH + h);
      *(s16x8*)&dst[(bh * SS + ss) * HD + d] = v;
    }
  }
}

// ---------------- proj GEMM: 256x256 8-phase (r7 form) -----------------------
__global__ __launch_bounds__(512, 2) void proj_gemm_kernel(
    const u16* __restrict__ A, const u16* __restrict__ Bt,
    const float* __restrict__ bias, float* __restrict__ out){
  const int K = 768, NT = 12;
  __shared__ u16 As[2][256*64];
  __shared__ u16 Bs[2][256*64];
  int tid = threadIdx.x;

  int gx = gridDim.x;
  int nwg = gx * gridDim.y;
  int L = blockIdx.y * gx + blockIdx.x;
  int nl = (L & 7) * (nwg >> 3) + (L >> 3);
  int m0 = (nl / gx) * 256, n0 = (nl % gx) * 256;

  int w = tid >> 6, lane = tid & 63, quad = lane >> 4, l15 = lane & 15;
  int wm = (w >> 2) * 128, wn = (w & 3) * 64;
  int rr = lane >> 3;
  int cp = lane & 7;
  f32x4 acc[8][4] = {};

  auto stageQ = [&](int t, int q){
    int d = t & 1, k0 = t * 64;
    const u16* src = (q < 2) ? A : Bt;
    int base = (q < 2) ? m0 : n0;
    u16* dst = (q < 2) ? As[d] : Bs[d];
    int h = q & 1;
    #pragma unroll
    for(int it = 0; it < 2; ++it){
      int ci = h*16 + it*8 + w;
      int r  = ci * 8 + rr;
      int gc = (cp ^ (r & 7)) * 8;
      __builtin_amdgcn_global_load_lds(
          (GLOBAL_AS)(src + (size_t)(base + r) * K + k0 + gc),
          (LDS_AS)(dst + ci * 512 + lane * 8), 16, 0, 0);
    }
  };

  s16x8 a[8], b0[4], b1[4];
  auto dsA = [&](int d, int mh){
    #pragma unroll
    for(int kk = 0; kk < 2; ++kk){
      int ch = ((kk*4 + quad) ^ (l15 & 7)) * 8;
      #pragma unroll
      for(int i = 0; i < 4; ++i)
        a[kk*4+i] = *(const s16x8*)&As[d][(wm + (mh*4+i)*16 + l15) * 64 + ch];
    }
  };
  auto dsB = [&](int d, int nh, s16x8* bb){
    #pragma unroll
    for(int kk = 0; kk < 2; ++kk){
      int ch = ((kk*4 + quad) ^ (l15 & 7)) * 8;
      #pragma unroll
      for(int j = 0; j < 2; ++j)
        bb[kk*2+j] = *(const s16x8*)&Bs[d][(wn + (nh*2+j)*16 + l15) * 64 + ch];
    }
  };
  auto mfmaQ = [&](int mh, int nh, const s16x8* bb){
    __builtin_amdgcn_s_setprio(1);
    #pragma unroll
    for(int kk = 0; kk < 2; ++kk)
      #pragma unroll
      for(int i = 0; i < 4; ++i)
        #pragma unroll
        for(int j = 0; j < 2; ++j)
          acc[mh*4+i][nh*2+j] = mfma16(a[kk*4+i], bb[kk*2+j], acc[mh*4+i][nh*2+j]);
    __builtin_amdgcn_s_setprio(0);
  };

#define PHASE_SYNC() do{ \
    __builtin_amdgcn_s_barrier(); \
    asm volatile("s_waitcnt lgkmcnt(0)" ::: "memory"); \
    __builtin_amdgcn_sched_barrier(0); \
  }while(0)
#define PHASE_END() do{ \
    __builtin_amdgcn_s_barrier(); \
    __builtin_amdgcn_sched_barrier(0); \
  }while(0)

  stageQ(0,0); stageQ(0,1); stageQ(0,2); stageQ(0,3);
  stageQ(1,0);
  asm volatile("s_waitcnt vmcnt(2)" ::: "memory");
  __builtin_amdgcn_s_barrier();
  __builtin_amdgcn_sched_barrier(0);

  #pragma unroll
  for(int j = 0; j < NT/2; ++j){
    int t = 2*j;
    stageQ(t+1, 1);
    dsA(0, 0); dsB(0, 0, b0);
    PHASE_SYNC(); mfmaQ(0, 0, b0); PHASE_END();
    stageQ(t+1, 2);
    dsB(0, 1, b1);
    PHASE_SYNC(); mfmaQ(0, 1, b1); PHASE_END();
    stageQ(t+1, 3);
    dsA(0, 1);
    PHASE_SYNC(); mfmaQ(1, 0, b0); PHASE_END();
    if(t+2 < NT){ stageQ(t+2, 0); asm volatile("s_waitcnt vmcnt(2)" ::: "memory"); }
    else        { asm volatile("s_waitcnt vmcnt(0)" ::: "memory"); }
    PHASE_SYNC(); mfmaQ(1, 1, b1); PHASE_END();
    if(t+2 < NT) stageQ(t+2, 1);
    dsA(1, 0); dsB(1, 0, b0);
    PHASE_SYNC(); mfmaQ(0, 0, b0); PHASE_END();
    if(t+2 < NT) stageQ(t+2, 2);
    dsB(1, 1, b1);
    PHASE_SYNC(); mfmaQ(0, 1, b1); PHASE_END();
    if(t+2 < NT) stageQ(t+2, 3);
    dsA(1, 1);
    PHASE_SYNC(); mfmaQ(1, 0, b0); PHASE_END();
    if(t+3 < NT){ stageQ(t+3, 0); asm volatile("s_waitcnt vmcnt(2)" ::: "memory"); }
    else if(t+2 < NT){ asm volatile("s_waitcnt vmcnt(0)" ::: "memory"); }
    PHASE_SYNC(); mfmaQ(1, 1, b1); PHASE_END();
  }
#undef PHASE_SYNC
#undef PHASE_END

  #pragma unroll
  for(int mt = 0; mt < 8; ++mt){
    #pragma unroll
    for(int nt = 0; nt < 4; ++nt){
      int n = n0 + wn + nt*16 + l15;
      float bv = bias[n];
      #pragma unroll
      for(int r = 0; r < 4; ++r){
        int m = m0 + wm + mt*16 + quad*4 + r;
        out[(size_t)m * EMB + n] = acc[mt][nt][r] + bv;
      }
    }
  }
}

// ---------------- attention: 512-thread blocks (8 waves, 256 q-rows) ---------
// r11 form (2 blocks/CU = 16 waves/CU), UNCHANGED.
__global__ __launch_bounds__(512) void attn_kernel(
    const u16* __restrict__ Qws, const u16* __restrict__ Kws,
    const u16* __restrict__ Vtws, u16* __restrict__ attn){
  __shared__ u16 Ks[2][64*64];                    // [key][d]   16 KB
  __shared__ u16 Vs[2][64*64];                    // [d][key]   16 KB
  __shared__ __align__(16) u16 Ps[8][2][16][76];  // [wave][m][q][key] 38.9 KB
  int tid = threadIdx.x;
  int w = tid >> 6, lane = tid & 63, quad = lane >> 4, l15 = lane & 15;
  int bh = blockIdx.x;                 // x=bh: all q-blocks of a bh -> same XCD
  int b = bh / NH, h = bh - b * NH;
  int q0 = blockIdx.y * 256 + w * 32;
  const u16* Qbase = Qws  + (size_t)bh * SS * HD;
  const u16* Kbase = Kws  + (size_t)bh * SS * HD;
  const u16* Vbase = Vtws + (size_t)bh * HD * SS;

  s16x8 aq[2][2];
  #pragma unroll
  for(int m = 0; m < 2; m++){
    int qrow = q0 + m*16 + l15;
    #pragma unroll
    for(int kk = 0; kk < 2; kk++)
      aq[m][kk] = *(const s16x8*)(Qbase + (size_t)qrow * HD + kk*32 + quad*8);
  }

  f32x4 o[2][4] = {};
  float psum[2][4] = {};
  const float C1 = 0.125f * 1.44269504f;
  const float C0 = -30.0f * 1.44269504f;

  int krr = lane >> 3, kcp = lane & 7;   // staging decode: 8 rows x 8 chunks

  auto stageKV = [&](int p, int kt){
    int ins = w;                         // 8 waves cover 8 row-groups
    int r   = ins * 8 + krr;             // 0..63
    int gck = (kcp ^ (r & 7)) * 8;
    __builtin_amdgcn_global_load_lds(
        (GLOBAL_AS)(Kbase + (size_t)(kt*64 + r) * HD + gck),
        (LDS_AS)(Ks[p] + ins * 512 + lane * 8), 16, 0, 0);
    __builtin_amdgcn_global_load_lds(
        (GLOBAL_AS)(Vbase + (size_t)r * SS + kt*64 + gck),
        (LDS_AS)(Vs[p] + ins * 512 + lane * 8), 16, 0, 0);
  };

  stageKV(0, 0);
  int p = 0;
  for(int kt = 0; kt < 16; ++kt){        // 64 keys per iteration
    __syncthreads();                     // drains stage(p); publishes buf p
    if(kt < 15) stageKV(p ^ 1, kt + 1);  // prefetch overlaps compute

    // scores + exp + P  (4 key-tiles of 16)
    #pragma unroll
    for(int nt = 0; nt < 4; ++nt){
      s16x8 bk[2];
      #pragma unroll
      for(int kk = 0; kk < 2; kk++){
        int ch = ((kk*4 + quad) ^ (l15 & 7)) * 8;
        bk[kk] = *(const s16x8*)&Ks[p][(nt*16 + l15) * 64 + ch];
      }
      #pragma unroll
      for(int m = 0; m < 2; m++){
        f32x4 z = {};
        z = mfma16(aq[m][0], bk[0], z);
        z = mfma16(aq[m][1], bk[1], z);
        #pragma unroll
        for(int r = 0; r < 4; r++){
          float pv = EXP2(z[r] * C1 + C0);
          psum[m][r] += pv;
          Ps[w][m][quad*4 + r][nt*16 + l15] = f2bf_trunc(pv);
        }
      }
    }
    // PV: o(2x16x64) += P(2x16x64) @ V(64x64)
    #pragma unroll
    for(int k4 = 0; k4 < 2; k4++){
      s16x8 pa[2];
      #pragma unroll
      for(int m = 0; m < 2; m++)
        pa[m] = *(const s16x8*)&Ps[w][m][l15][k4*32 + quad*8];
      #pragma unroll
      for(int nt = 0; nt < 4; nt++){
        int ch = ((k4*4 + quad) ^ (l15 & 7)) * 8;
        s16x8 vb = *(const s16x8*)&Vs[p][(nt*16 + l15) * 64 + ch];
        #pragma unroll
        for(int m = 0; m < 2; m++)
          o[m][nt] = mfma16(pa[m], vb, o[m][nt]);
      }
    }
    p ^= 1;
  }

  // epilogue: out[b, s, h*64+d] = o / rowsum
  #pragma unroll
  for(int m = 0; m < 2; m++){
    #pragma unroll
    for(int r = 0; r < 4; r++){
      float s = psum[m][r];
      s += __shfl_xor(s, 1, 64);
      s += __shfl_xor(s, 2, 64);
      s += __shfl_xor(s, 4, 64);
      s += __shfl_xor(s, 8, 64);
      float inv = 1.0f / s;
      int srow = q0 + m*16 + quad*4 + r;
      size_t base = ((size_t)(b * SS + srow)) * EMB + h * HD;
      #pragma unroll
      for(int nt = 0; nt < 4; nt++)
        attn[base + nt*16 + l15] = f2bf(o[m][nt][r] * inv);
    }
  }
}

extern "C" void kernel_launch(void* const* d_in, const int* in_sizes, int n_in,
                              void* d_out, int out_size, void* d_ws, size_t ws_size,
                              hipStream_t stream){
  const float* x      = (const float*)d_in[0];
  const float* qkv_w  = (const float*)d_in[1];
  const float* qkv_b  = (const float*)d_in[2];
  const float* proj_w = (const float*)d_in[3];
  const float* proj_b = (const float*)d_in[4];

  char* ws = (char*)d_ws;
  u16* qkv_wT  = (u16*)ws; ws += (size_t)NQKV * EMB * 2;   // [2304,768] bf16
  u16* proj_wT = (u16*)ws; ws += (size_t)EMB * EMB * 2;    // [768,768] bf16
  u16* x_bf = (u16*)ws; ws += QSZ * 2;   // [16384,768] bf16; reused as attn out
  u16* Qws  = (u16*)ws; ws += QSZ * 2;                     // [bh,S,D]
  u16* Kws  = (u16*)ws; ws += QSZ * 2;                     // [bh,S,D]
  u16* Vtws = (u16*)ws; ws += QSZ * 2;                     // [bh,D,S]
  u16* attn = x_bf;

  prep_kernel<<<NBA + NBB + NBC, 256, 0, stream>>>(
      (const float4*)x, (ushort4*)x_bf, qkv_w, qkv_wT, proj_w, proj_wT);
  qkv_gemm_kernel<<<dim3(NQKV/128, MTOK/128), 256, 0, stream>>>(
      x_bf, qkv_wT, qkv_b, Qws, Kws, Vtws);
  attn_kernel<<<dim3(BB*NH, SS/256), 512, 0, stream>>>(Qws, Kws, Vtws, attn);
  proj_gemm_kernel<<<dim3(EMB/256, MTOK/256), 512, 0, stream>>>(
      attn, proj_wT, proj_b, (float*)d_out);
}